// Round 13
// baseline (538.731 us; speedup 1.0000x reference)
//
#include <hip/hip_runtime.h>
#include <hip/hip_cooperative_groups.h>

namespace cg = cooperative_groups;

// Problem constants
#define BGR   256
#define NPG   128
#define EPG   512
#define DIN   128
#define DD    256
#define DD2   512
#define NTOT  (BGR * NPG)
#define ETOT  (BGR * EPG)
#define NRES  (EPG / 2)
#define MP    136            // padded stride (ushorts)

// LDS layout (bytes)
#define SM_A  0              // 34816: Ms [128][136] (persists P1..P5)
#define SM_H  34816          // 69632: cnt(P1) / S1 / h1T / PT / S2 halves / h2T
#define SM_B  104448         // 36864: XT / Wc / Cs / As+Bs / sort arrays
#define SM_S  141312         // 8192: scs(2048) shs(2048) redS(1024) redQ(1024) pa/pb(1024)
#define SM_TOTAL 149504

// Output layout (floats)
#define OFF_CEI  0
#define OFF_CW   (2 * BGR * NRES)
#define OFF_FEI  (OFF_CW + BGR * NRES)
#define OFF_FW   (OFF_FEI + 2 * BGR * NRES)
#define OFF_PRED (OFF_FW + BGR * NRES)

typedef unsigned short ushortt;
typedef __attribute__((ext_vector_type(8))) unsigned short us8;
typedef __attribute__((ext_vector_type(8))) short short8;
typedef __attribute__((ext_vector_type(4))) float f32x4;

__device__ __forceinline__ ushortt f2bf(float f) {
    unsigned int u = __float_as_uint(f);
    unsigned int r = (u + 0x7fffu + ((u >> 16) & 1u)) >> 16;
    return (ushortt)r;
}
__device__ __forceinline__ float bf2f(ushortt u) {
    return __uint_as_float(((unsigned int)u) << 16);
}
__device__ __forceinline__ void g2lds16(const void* g, void* l) {
    __builtin_amdgcn_global_load_lds(
        (const __attribute__((address_space(1))) unsigned int*)g,
        (__attribute__((address_space(3))) unsigned int*)l, 16, 0, 0);
}

// 8-wave 2x4 MFMA tile: 128x128 output, K=128, both operands [*][MP] in LDS.
__device__ __forceinline__ void mfma_tile_ld(const ushortt* Ap, const ushortt* Bp,
                                             int wm, int wn, int qd, int r,
                                             f32x4 acc[4][2]) {
#pragma unroll
    for (int ks = 0; ks < 4; ++ks) {
        const int k0 = ks * 32 + qd * 8;
        short8 af[4], bfr[2];
#pragma unroll
        for (int i = 0; i < 4; ++i)
            af[i] = *(const short8*)&Ap[(wm + i * 16 + r) * MP + k0];
#pragma unroll
        for (int j = 0; j < 2; ++j)
            bfr[j] = *(const short8*)&Bp[(wn + j * 16 + r) * MP + k0];
#pragma unroll
        for (int i = 0; i < 4; ++i)
#pragma unroll
            for (int j = 0; j < 2; ++j)
                acc[i][j] = __builtin_amdgcn_mfma_f32_16x16x32_bf16(af[i], bfr[j], acc[i][j], 0, 0, 0);
    }
}

__device__ __forceinline__ void scatter_rowmajor(ushortt* dst, f32x4 acc[4][2],
                                                 int wm, int wn, int qd, int r) {
#pragma unroll
    for (int j = 0; j < 2; ++j) {
        const int col = wn + j * 16 + r;
#pragma unroll
        for (int i = 0; i < 4; ++i)
#pragma unroll
            for (int tt = 0; tt < 4; ++tt)
                dst[(wm + i * 16 + qd * 4 + tt) * MP + col] = f2bf(acc[i][j][tt]);
    }
}

// z-GEMM phase: C[128 x 512] = A(SM_H, khn halves) @ Wt^T + bias -> zb + stats
__device__ __forceinline__ void zgemm_phase(char* smem, int b, int t,
                                            const ushortt* __restrict__ Wt, int wtStride, int khn,
                                            const float* __restrict__ bias,
                                            ushortt* __restrict__ zb,
                                            float* __restrict__ psA, float* __restrict__ pqA) {
    const int wave = t >> 6, lane = t & 63;
    const int qd = lane >> 4, r = lane & 15;
    const int wm = (wave >> 2) * 64, wn = (wave & 3) * 32;
    ushortt* Wc = (ushortt*)(smem + SM_B);
    float* redS = (float*)(smem + SM_S + 4096);
    float* redQ = (float*)(smem + SM_S + 5120);
    for (int nc = 0; nc < 4; ++nc) {
        f32x4 acc[4][2] = {};
        for (int kh = 0; kh < khn; ++kh) {
#pragma unroll
            for (int kk = 0; kk < 4; ++kk) {
                const int ch = t + kk * 512;
                const int n = ch >> 4, k8 = (ch & 15) * 8;
                *(us8*)&Wc[n * MP + k8] =
                    *(const us8*)&Wt[(size_t)(nc * 128 + n) * wtStride + kh * 128 + k8];
            }
            __syncthreads();
            const ushortt* Ap = (const ushortt*)(smem + SM_H) + kh * 17408;
            mfma_tile_ld(Ap, Wc, wm, wn, qd, r, acc);
            __syncthreads();
        }
        ushortt* Cs = Wc;
#pragma unroll
        for (int j = 0; j < 2; ++j) {
            const int coll = wn + j * 16 + r;
            const float bv = bias[nc * 128 + coll];
            float s = 0.f, q = 0.f;
#pragma unroll
            for (int i = 0; i < 4; ++i)
#pragma unroll
                for (int tt = 0; tt < 4; ++tt) {
                    const float v = acc[i][j][tt] + bv;
                    Cs[(wm + i * 16 + qd * 4 + tt) * MP + coll] = f2bf(v);
                    s += v; q = fmaf(v, v, q);
                }
            s += __shfl_xor(s, 16); s += __shfl_xor(s, 32);
            q += __shfl_xor(q, 16); q += __shfl_xor(q, 32);
            if (qd == 0) { redS[(wm >> 6) * 128 + coll] = s; redQ[(wm >> 6) * 128 + coll] = q; }
        }
        __syncthreads();
        if (t < 128) {
            psA[(size_t)b * DD2 + nc * 128 + t] = redS[t] + redS[128 + t];
            pqA[(size_t)b * DD2 + nc * 128 + t] = redQ[t] + redQ[128 + t];
        }
#pragma unroll
        for (int kk = 0; kk < 4; ++kk) {
            const int ch = t + kk * 512;
            const int row = ch >> 4, colc = (ch & 15) * 8;
            *(us8*)&zb[(size_t)(b * NPG + row) * DD2 + nc * 128 + colc] =
                *(const us8*)&Cs[row * MP + colc];
        }
        __syncthreads();
    }
}

// h-GEMM phase: hT[256 c][136] = relu(BN(z)) @ Wt^T + bias (LDS out) + stats
__device__ __forceinline__ void hgemm_phase(char* smem, int b, int t,
                                            const ushortt* __restrict__ zglob,
                                            const ushortt* __restrict__ Wt,
                                            const float* __restrict__ scAg,
                                            const float* __restrict__ shAg,
                                            const float* __restrict__ bias,
                                            float* __restrict__ psB, float* __restrict__ pqB) {
    const int wave = t >> 6, lane = t & 63;
    const int qd = lane >> 4, r = lane & 15;
    const int wm = (wave >> 2) * 64, wn = (wave & 3) * 32;
    float* scs = (float*)(smem + SM_S);
    float* shs = scs + 512;
    float* redS = (float*)(smem + SM_S + 4096);
    float* redQ = (float*)(smem + SM_S + 5120);
    ushortt* As = (ushortt*)(smem + SM_B);
    ushortt* Bs = As + 4096;
    ushortt* hT = (ushortt*)(smem + SM_H);
    scs[t] = scAg[t]; shs[t] = shAg[t];
    __syncthreads();
    const int row = t >> 2, cg = t & 3;
    for (int nc = 0; nc < 2; ++nc) {
        f32x4 acc[4][2] = {};
        for (int k0 = 0; k0 < DD2; k0 += 32) {
            g2lds16(Wt + (size_t)(nc * 128 + row) * DD2 + k0 + cg * 8,
                    &Bs[(size_t)(wave * 64) * 8]);
            {
                const us8 a8 = *(const us8*)&zglob[(size_t)(b * NPG + row) * DD2 + k0 + cg * 8];
                const float4 s4a = *(const float4*)&scs[k0 + cg * 8];
                const float4 s4b = *(const float4*)&scs[k0 + cg * 8 + 4];
                const float4 h4a = *(const float4*)&shs[k0 + cg * 8];
                const float4 h4b = *(const float4*)&shs[k0 + cg * 8 + 4];
                us8 t8;
                t8[0] = f2bf(fmaxf(fmaf(bf2f(a8[0]), s4a.x, h4a.x), 0.0f));
                t8[1] = f2bf(fmaxf(fmaf(bf2f(a8[1]), s4a.y, h4a.y), 0.0f));
                t8[2] = f2bf(fmaxf(fmaf(bf2f(a8[2]), s4a.z, h4a.z), 0.0f));
                t8[3] = f2bf(fmaxf(fmaf(bf2f(a8[3]), s4a.w, h4a.w), 0.0f));
                t8[4] = f2bf(fmaxf(fmaf(bf2f(a8[4]), s4b.x, h4b.x), 0.0f));
                t8[5] = f2bf(fmaxf(fmaf(bf2f(a8[5]), s4b.y, h4b.y), 0.0f));
                t8[6] = f2bf(fmaxf(fmaf(bf2f(a8[6]), s4b.z, h4b.z), 0.0f));
                t8[7] = f2bf(fmaxf(fmaf(bf2f(a8[7]), s4b.w, h4b.w), 0.0f));
                *(us8*)&As[row * 32 + cg * 8] = t8;
            }
            __syncthreads();
            short8 af[4], bfr[2];
            const int kq = qd * 8;
#pragma unroll
            for (int i = 0; i < 4; ++i)
                af[i] = *(const short8*)&As[(wm + i * 16 + r) * 32 + kq];
#pragma unroll
            for (int j = 0; j < 2; ++j)
                bfr[j] = *(const short8*)&Bs[(wn + j * 16 + r) * 32 + kq];
#pragma unroll
            for (int i = 0; i < 4; ++i)
#pragma unroll
                for (int j = 0; j < 2; ++j)
                    acc[i][j] = __builtin_amdgcn_mfma_f32_16x16x32_bf16(af[i], bfr[j], acc[i][j], 0, 0, 0);
            __syncthreads();
        }
#pragma unroll
        for (int j = 0; j < 2; ++j) {
            const int coll = wn + j * 16 + r;
            const float bv = bias[nc * 128 + coll];
            float s = 0.f, q = 0.f;
#pragma unroll
            for (int i = 0; i < 4; ++i)
#pragma unroll
                for (int tt = 0; tt < 4; ++tt) {
                    const float v = acc[i][j][tt] + bv;
                    hT[(nc * 128 + coll) * 136 + (wm + i * 16 + qd * 4 + tt)] = f2bf(v);
                    s += v; q = fmaf(v, v, q);
                }
            s += __shfl_xor(s, 16); s += __shfl_xor(s, 32);
            q += __shfl_xor(q, 16); q += __shfl_xor(q, 32);
            if (qd == 0) { redS[(wm >> 6) * 128 + coll] = s; redQ[(wm >> 6) * 128 + coll] = q; }
        }
        __syncthreads();
        if (t < 128) {
            psB[(size_t)b * DD + nc * 128 + t] = redS[t] + redS[128 + t];
            pqB[(size_t)b * DD + nc * 128 + t] = redQ[t] + redQ[128 + t];
        }
        __syncthreads();
    }
}

__device__ __forceinline__ void finalize_cols(const float* __restrict__ ps,
                                              const float* __restrict__ pq,
                                              const float* __restrict__ g,
                                              const float* __restrict__ be,
                                              int ncols, int t,
                                              float* __restrict__ scg,
                                              float* __restrict__ shg) {
    if (t < ncols) {
        double s = 0.0, s2 = 0.0;
        for (int k = 0; k < 256; ++k) {
            s += (double)ps[(size_t)k * ncols + t];
            s2 += (double)pq[(size_t)k * ncols + t];
        }
        const double mean = s / (double)NTOT;
        const double var = s2 / (double)NTOT - mean * mean;
        const double rs = 1.0 / sqrt(var + 1e-5);
        const float sc = (float)((double)g[t] * rs);
        scg[t] = sc;
        shg[t] = (float)((double)be[t] - mean * (double)sc);
    }
}

// ---------------------------------------------------------------------------
__global__ __launch_bounds__(512, 2) void mega(
    const float* __restrict__ x, const int* __restrict__ ei,
    const float* __restrict__ vemb,
    const float* __restrict__ W1a, const float* __restrict__ b1a,
    const float* __restrict__ g1a, const float* __restrict__ be1a,
    const float* __restrict__ W1b, const float* __restrict__ b1b,
    const float* __restrict__ g1, const float* __restrict__ be1,
    const float* __restrict__ W2a, const float* __restrict__ b2a,
    const float* __restrict__ g2a, const float* __restrict__ be2a,
    const float* __restrict__ W2b, const float* __restrict__ b2b,
    const float* __restrict__ g2, const float* __restrict__ be2,
    const float* __restrict__ Wl, const float* __restrict__ bl,
    ushortt* __restrict__ zb,
    ushortt* __restrict__ Wt1a, ushortt* __restrict__ Wt1b,
    ushortt* __restrict__ Wt2a, ushortt* __restrict__ Wt2b,
    float* __restrict__ psA, float* __restrict__ pqA,
    float* __restrict__ psB, float* __restrict__ pqB,
    float* __restrict__ scAg, float* __restrict__ shAg,
    float* __restrict__ scBg, float* __restrict__ shBg,
    float* __restrict__ out) {
    __shared__ __align__(16) char smem[SM_TOTAL];
    cg::grid_group grid = cg::this_grid();
    const int b = blockIdx.x;
    const int t = threadIdx.x;
    const int wave = t >> 6, lane = t & 63;
    const int qd = lane >> 4, r = lane & 15;
    const int wm = (wave >> 2) * 64, wn = (wave & 3) * 32;

    // ---- P0: weight transposes (blocks 0..111), 64x64 tiles
    if (b < 112) {
        const float* W; ushortt* Wt; int Nsrc, Ktot, kr0, nc0;
        if (b < 16)      { W = W1a; Wt = Wt1a; Nsrc = 512; Ktot = 128; kr0 = (b >> 3) * 64; nc0 = (b & 7) * 64; }
        else if (b < 48) { const int i = b - 16; W = W1b; Wt = Wt1b; Nsrc = 256; Ktot = 512; kr0 = (i >> 2) * 64; nc0 = (i & 3) * 64; }
        else if (b < 80) { const int i = b - 48; W = W2a; Wt = Wt2a; Nsrc = 512; Ktot = 256; kr0 = (i >> 3) * 64; nc0 = (i & 7) * 64; }
        else             { const int i = b - 80; W = W2b; Wt = Wt2b; Nsrc = 256; Ktot = 512; kr0 = (i >> 2) * 64; nc0 = (i & 3) * 64; }
        ushortt* tile = (ushortt*)smem;
#pragma unroll
        for (int kk = 0; kk < 2; ++kk) {
            const int idx = t + kk * 512;
            const int rr = idx >> 4, c4 = (idx & 15) * 4;
            const float4 v = *(const float4*)&W[(size_t)(kr0 + rr) * Nsrc + nc0 + c4];
            tile[rr * 67 + c4 + 0] = f2bf(v.x);
            tile[rr * 67 + c4 + 1] = f2bf(v.y);
            tile[rr * 67 + c4 + 2] = f2bf(v.z);
            tile[rr * 67 + c4 + 3] = f2bf(v.w);
        }
        __syncthreads();
        {
            const int n = t >> 3, k8 = (t & 7) * 8;
            us8 o;
#pragma unroll
            for (int j = 0; j < 8; ++j) o[j] = tile[(k8 + j) * 67 + n];
            *(us8*)&Wt[(size_t)(nc0 + n) * Ktot + kr0 + k8] = o;
        }
        __syncthreads();
    }

    // ---- P1: adjacency -> Ms (persists); s1 = Ms @ bf16(x)^T -> SM_H
    {
        int* cnt = (int*)(smem + SM_H);
        ushortt* Ms = (ushortt*)(smem + SM_A);
        ushortt* XT = (ushortt*)(smem + SM_B);
        for (int i = t; i < NPG * NPG; i += 512) cnt[i] = 0;
        __syncthreads();
        {
            const int src = ei[b * EPG + t] - b * NPG;
            const int dst = ei[ETOT + b * EPG + t] - b * NPG;
            atomicAdd(&cnt[dst * NPG + src], 1);
        }
        __syncthreads();
#pragma unroll
        for (int kk = 0; kk < 4; ++kk) {
            const int ch = t + kk * 512;
            const int m = ch >> 4, sc0 = (ch & 15) * 8;
            us8 o;
#pragma unroll
            for (int e2 = 0; e2 < 8; ++e2)
                o[e2] = f2bf((float)(cnt[m * NPG + sc0 + e2] + (m == sc0 + e2 ? 1 : 0)));
            *(us8*)&Ms[m * MP + sc0] = o;
        }
#pragma unroll
        for (int kk = 0; kk < 4; ++kk) {
            const int ch = t + kk * 512;
            const int c = ch & 127, s8 = ch >> 7;
            us8 o;
#pragma unroll
            for (int j = 0; j < 8; ++j)
                o[j] = f2bf(x[(size_t)(b * NPG + s8 * 8 + j) * DIN + c]);
            *(us8*)&XT[c * MP + s8 * 8] = o;
        }
        __syncthreads();
        f32x4 acc[4][2] = {};
        mfma_tile_ld(Ms, XT, wm, wn, qd, r, acc);
        __syncthreads();     // cnt fully dead; Ms/XT reads done
        scatter_rowmajor((ushortt*)(smem + SM_H), acc, wm, wn, qd, r);
        __syncthreads();
    }
    grid.sync();   // S1: weights ready

    // ---- P2: z1 = s1 @ W1a^T + b1a
    zgemm_phase(smem, b, t, Wt1a, DIN, 1, b1a, zb, psA, pqA);
    grid.sync();   // S2
    if (b == 0) finalize_cols(psA, pqA, g1a, be1a, DD2, t, scAg, shAg);
    grid.sync();   // S2b

    // ---- P3: h1T = relu(BN(z1)) @ W1b^T + b1b (LDS)
    hgemm_phase(smem, b, t, zb, Wt1b, scAg, shAg, b1b, psB, pqB);
    grid.sync();   // S3
    if (b == 0) finalize_cols(psB, pqB, g1, be1, DD, t, scBg, shBg);
    grid.sync();   // S3b

    // ---- P5: PT = relu(BN(h1T))+vemb (in place); s2 = Ms @ PT (LDS halves)
    {
        float* scs = (float*)(smem + SM_S);
        float* shs = scs + 512;
        if (t < DD) { scs[t] = scBg[t]; shs[t] = shBg[t]; }
        __syncthreads();
        ushortt* hT = (ushortt*)(smem + SM_H);
#pragma unroll
        for (int kk = 0; kk < 8; ++kk) {
            const int ch = t + kk * 512;
            const int c = ch >> 4, s8 = (ch & 15) * 8;
            const us8 v = *(const us8*)&hT[c * 136 + s8];
            const float scv = scs[c], shv = shs[c], vev = vemb[c];
            us8 o;
#pragma unroll
            for (int j = 0; j < 8; ++j)
                o[j] = f2bf(fmaxf(fmaf(bf2f(v[j]), scv, shv), 0.0f) + vev);
            *(us8*)&hT[c * 136 + s8] = o;
        }
        __syncthreads();
        const ushortt* Ms = (const ushortt*)(smem + SM_A);
        for (int h = 0; h < 2; ++h) {
            f32x4 acc[4][2] = {};
            mfma_tile_ld(Ms, hT + h * 17408, wm, wn, qd, r, acc);
            __syncthreads();
            scatter_rowmajor((ushortt*)(smem + SM_H) + h * 17408, acc, wm, wn, qd, r);
            __syncthreads();
        }
    }

    // ---- P6: z2 = s2 @ W2a^T + b2a
    zgemm_phase(smem, b, t, Wt2a, DD, 2, b2a, zb, psA, pqA);
    grid.sync();   // S4
    if (b == 0) finalize_cols(psA, pqA, g2a, be2a, DD2, t, scAg, shAg);
    grid.sync();   // S4b

    // ---- P7: h2T = relu(BN(z2)) @ W2b^T + b2b (LDS)
    hgemm_phase(smem, b, t, zb, Wt2b, scAg, shAg, b2b, psB, pqB);
    grid.sync();   // S5
    if (b == 0) finalize_cols(psB, pqB, g2, be2, DD, t, scBg, shBg);
    grid.sync();   // S5b

    // ---- P8: dots + scores + stable sort + writes
    {
        float* scs = (float*)(smem + SM_S);
        float* shs = scs + 512;
        if (t < DD) { scs[t] = scBg[t]; shs[t] = shBg[t]; }
        __syncthreads();
        const ushortt* hT = (const ushortt*)(smem + SM_H);
        float* part  = (float*)(smem + SM_B);          // [4][128]
        float* partb = part + 512;                     // [4][128]
        {
            const int node = lane + (wave & 1) * 64;
            const int cb = (wave >> 1) * 64;
            float sa = 0.f, sb = 0.f;
            for (int cc = 0; cc < 64; ++cc) {
                const int c = cb + cc;
                const float xv = fmaf(bf2f(hT[c * 136 + node]), scs[c], shs[c]);
                sa = fmaf(xv, Wl[c], sa);
                sb = fmaf(xv, Wl[DD + c], sb);
            }
            part[(wave >> 1) * 128 + node] = sa;
            partb[(wave >> 1) * 128 + node] = sb;
        }
        __syncthreads();
        float* pa = (float*)(smem + SM_S + 6144);
        float* pb = pa + 128;
        if (t < 128) {
            pa[t] = part[t] + part[128 + t] + part[256 + t] + part[384 + t];
            pb[t] = partb[t] + partb[128 + t] + partb[256 + t] + partb[384 + t];
        }
        __syncthreads();
        float* pw = (float*)(smem + SM_B);             // aliases part (dead)
        int* ord = (int*)(smem + SM_B + 2048);
        const int rl = ei[b * EPG + t] - b * NPG;
        const int cl = ei[ETOT + b * EPG + t] - b * NPG;
        const float v = pa[rl] + pb[cl] + bl[0];
        pw[t] = v;
        out[OFF_PRED + b * EPG + t] = v;
        __syncthreads();
        int rank = 0;
#pragma unroll 8
        for (int k = 0; k < EPG; ++k) {
            const float u = pw[k];
            rank += (u > v) || (u == v && k < t);
        }
        ord[rank] = t;
        __syncthreads();
        const int j = ord[t];
        const float wv = pw[j];
        const float e0 = (float)ei[b * EPG + j];
        const float e1 = (float)ei[ETOT + b * EPG + j];
        if (t < NRES) {
            out[OFF_CEI + b * NRES + t] = e0;
            out[OFF_CEI + BGR * NRES + b * NRES + t] = e1;
            out[OFF_CW + b * NRES + t] = wv;
        } else {
            const int p = t - NRES;
            out[OFF_FEI + b * NRES + p] = e0;
            out[OFF_FEI + BGR * NRES + b * NRES + p] = e1;
            out[OFF_FW + b * NRES + p] = -wv;
        }
    }
}

// ---------------------------------------------------------------------------
extern "C" void kernel_launch(void* const* d_in, const int* in_sizes, int n_in,
                              void* d_out, int out_size, void* d_ws, size_t ws_size,
                              hipStream_t stream) {
    (void)in_sizes; (void)n_in; (void)out_size; (void)ws_size;
    const float* x    = (const float*)d_in[0];
    const int*   ei   = (const int*)d_in[1];
    const float* vemb = (const float*)d_in[3];
    const float* W1a  = (const float*)d_in[4];
    const float* b1a  = (const float*)d_in[5];
    const float* g1a  = (const float*)d_in[6];
    const float* be1a = (const float*)d_in[7];
    const float* W1b  = (const float*)d_in[8];
    const float* b1b  = (const float*)d_in[9];
    const float* g1   = (const float*)d_in[10];
    const float* be1  = (const float*)d_in[11];
    const float* W2a  = (const float*)d_in[12];
    const float* b2a  = (const float*)d_in[13];
    const float* g2a  = (const float*)d_in[14];
    const float* be2a = (const float*)d_in[15];
    const float* W2b  = (const float*)d_in[16];
    const float* b2b  = (const float*)d_in[17];
    const float* g2   = (const float*)d_in[18];
    const float* be2  = (const float*)d_in[19];
    const float* Wl   = (const float*)d_in[20];
    const float* bl   = (const float*)d_in[21];
    float* out = (float*)d_out;

    char* wp = (char*)d_ws;
    auto alloc = [&](size_t bytes) -> char* {
        char* r = wp;
        wp += (bytes + 255) & ~(size_t)255;
        return r;
    };
    ushortt* zb   = (ushortt*)alloc((size_t)NTOT * DD2 * 2);
    ushortt* Wt1a = (ushortt*)alloc((size_t)DIN * DD2 * 2);
    ushortt* Wt1b = (ushortt*)alloc((size_t)DD2 * DD * 2);
    ushortt* Wt2a = (ushortt*)alloc((size_t)DD * DD2 * 2);
    ushortt* Wt2b = (ushortt*)alloc((size_t)DD2 * DD * 2);
    float* psA = (float*)alloc((size_t)256 * DD2 * 4);
    float* pqA = (float*)alloc((size_t)256 * DD2 * 4);
    float* psB = (float*)alloc((size_t)256 * DD * 4);
    float* pqB = (float*)alloc((size_t)256 * DD * 4);
    float* scAg = (float*)alloc(DD2 * 4);
    float* shAg = (float*)alloc(DD2 * 4);
    float* scBg = (float*)alloc(DD * 4);
    float* shBg = (float*)alloc(DD * 4);

    void* kargs[] = {
        (void*)&x, (void*)&ei, (void*)&vemb,
        (void*)&W1a, (void*)&b1a, (void*)&g1a, (void*)&be1a,
        (void*)&W1b, (void*)&b1b, (void*)&g1, (void*)&be1,
        (void*)&W2a, (void*)&b2a, (void*)&g2a, (void*)&be2a,
        (void*)&W2b, (void*)&b2b, (void*)&g2, (void*)&be2,
        (void*)&Wl, (void*)&bl,
        (void*)&zb, (void*)&Wt1a, (void*)&Wt1b, (void*)&Wt2a, (void*)&Wt2b,
        (void*)&psA, (void*)&pqA, (void*)&psB, (void*)&pqB,
        (void*)&scAg, (void*)&shAg, (void*)&scBg, (void*)&shBg,
        (void*)&out
    };
    hipLaunchCooperativeKernel((const void*)mega, dim3(BGR), dim3(512),
                               kargs, 0, stream);
}

// Round 14
// 306.817 us; speedup vs baseline: 1.7559x; 1.7559x over previous
//
#include <hip/hip_runtime.h>

// Problem constants
#define BGR   256
#define NPG   128
#define EPG   512
#define DIN   128
#define DD    256
#define DD2   512
#define NTOT  (BGR * NPG)   // 32768
#define ETOT  (BGR * EPG)   // 131072
#define NRES  (EPG / 2)
#define NCHUNK 256
#define MP    136           // padded LDS stride (ushorts)

// Output layout (floats)
#define OFF_CEI  0
#define OFF_CW   (2 * BGR * NRES)
#define OFF_FEI  (OFF_CW + BGR * NRES)
#define OFF_FW   (OFF_FEI + 2 * BGR * NRES)
#define OFF_PRED (OFF_FW + BGR * NRES)

typedef unsigned short ushortt;
typedef __attribute__((ext_vector_type(4))) unsigned short us4;
typedef __attribute__((ext_vector_type(8))) unsigned short us8;
typedef __attribute__((ext_vector_type(8))) short short8;
typedef __attribute__((ext_vector_type(4))) float f32x4;

__device__ __forceinline__ ushortt f2bf(float f) {
    unsigned int u = __float_as_uint(f);
    unsigned int r = (u + 0x7fffu + ((u >> 16) & 1u)) >> 16;
    return (ushortt)r;
}
__device__ __forceinline__ float bf2f(ushortt u) {
    return __uint_as_float(((unsigned int)u) << 16);
}

__device__ __forceinline__ void g2lds16(const void* g, void* l) {
    __builtin_amdgcn_global_load_lds(
        (const __attribute__((address_space(1))) unsigned int*)g,
        (__attribute__((address_space(3))) unsigned int*)l, 16, 0, 0);
}

// ---------------------------------------------------------------------------
// prep: blocks 0..1791 transpose weights to bf16 [N][K]; blocks 1792..2047
// build per-graph adjacency (I + A^T), write Madj, and compute
// s1 = bf16(M @ bf16(x)) via MFMA entirely in LDS.
__global__ __launch_bounds__(256) void prep(const float* __restrict__ W1a,
                                            const float* __restrict__ W1b,
                                            const float* __restrict__ W2a,
                                            const float* __restrict__ W2b,
                                            const float* __restrict__ x,
                                            const int* __restrict__ ei,
                                            ushortt* __restrict__ Wt1a,
                                            ushortt* __restrict__ Wt1b,
                                            ushortt* __restrict__ Wt2a,
                                            ushortt* __restrict__ Wt2b,
                                            ushortt* __restrict__ Madj,
                                            ushortt* __restrict__ s1) {
    __shared__ __align__(16) char smem[102400];
    const int t = threadIdx.x;
    if (blockIdx.x < 1792) {
        const int idx = blockIdx.x * 256 + t;
        if (idx < 65536) {                       // W1a: 128x512
            const int k = idx >> 9, n = idx & 511;
            Wt1a[n * DIN + k] = f2bf(W1a[idx]);
        } else if (idx < 196608) {               // W1b: 512x256
            const int i = idx - 65536;
            const int k = i >> 8, n = i & 255;
            Wt1b[n * DD2 + k] = f2bf(W1b[i]);
        } else if (idx < 327680) {               // W2a: 256x512
            const int i = idx - 196608;
            const int k = i >> 9, n = i & 511;
            Wt2a[n * DD + k] = f2bf(W2a[i]);
        } else if (idx < 458752) {               // W2b: 512x256
            const int i = idx - 327680;
            const int k = i >> 8, n = i & 255;
            Wt2b[n * DD2 + k] = f2bf(W2b[i]);
        }
        return;
    }
    const int b = blockIdx.x - 1792;
    ushortt* Ms = (ushortt*)smem;                    // [128][136]
    int* cnt = (int*)(smem + 34816);                 // 64 KB
    ushortt* XT = (ushortt*)(smem + 34816);          // [128][136], after cnt dead
    ushortt* Cs = (ushortt*)(smem + 69632);          // [128][128]
    const int wave = t >> 6, lane = t & 63;
    const int qd = lane >> 4, r = lane & 15;
    const int wm = (wave >> 1) * 64, wn = (wave & 1) * 64;

    for (int i = t; i < NPG * NPG; i += 256) cnt[i] = 0;
    __syncthreads();
    for (int e = t; e < EPG; e += 256) {
        const int src = ei[b * EPG + e] - b * NPG;
        const int dst = ei[ETOT + b * EPG + e] - b * NPG;
        atomicAdd(&cnt[dst * NPG + src], 1);
    }
    __syncthreads();
#pragma unroll
    for (int k = 0; k < 8; ++k) {
        const int ch = t + k * 256;
        const int m = ch >> 4, sc = (ch & 15) * 8;
        us8 o;
#pragma unroll
        for (int e = 0; e < 8; ++e)
            o[e] = f2bf((float)(cnt[m * NPG + sc + e] + (m == sc + e ? 1 : 0)));
        *(us8*)&Ms[m * MP + sc] = o;
        *(us8*)&Madj[(size_t)b * NPG * NPG + m * NPG + sc] = o;
    }
    __syncthreads();

#pragma unroll
    for (int k = 0; k < 8; ++k) {
        const int ch = t + k * 256;
        const int c = ch & 127, s8 = ch >> 7;
        us8 o;
#pragma unroll
        for (int j = 0; j < 8; ++j)
            o[j] = f2bf(x[(size_t)(b * NPG + s8 * 8 + j) * DIN + c]);
        *(us8*)&XT[c * MP + s8 * 8] = o;
    }
    __syncthreads();

    f32x4 acc[4][4] = {};
#pragma unroll
    for (int ks = 0; ks < 4; ++ks) {
        const int k0 = ks * 32 + qd * 8;
        short8 af[4], bfr[4];
#pragma unroll
        for (int i = 0; i < 4; ++i)
            af[i] = *(const short8*)&Ms[(wm + i * 16 + r) * MP + k0];
#pragma unroll
        for (int j = 0; j < 4; ++j)
            bfr[j] = *(const short8*)&XT[(wn + j * 16 + r) * MP + k0];
#pragma unroll
        for (int i = 0; i < 4; ++i)
#pragma unroll
            for (int j = 0; j < 4; ++j)
                acc[i][j] = __builtin_amdgcn_mfma_f32_16x16x32_bf16(af[i], bfr[j], acc[i][j], 0, 0, 0);
    }
#pragma unroll
    for (int j = 0; j < 4; ++j) {
        const int coll = wn + j * 16 + r;
#pragma unroll
        for (int i = 0; i < 4; ++i)
#pragma unroll
            for (int tt = 0; tt < 4; ++tt)
                Cs[(wm + i * 16 + qd * 4 + tt) * 128 + coll] = f2bf(acc[i][j][tt]);
    }
    __syncthreads();
#pragma unroll
    for (int k = 0; k < 8; ++k) {
        const int ch = t + k * 256;
        const int row = ch >> 4, colc = (ch & 15) * 8;
        *(us8*)&s1[(size_t)(b * NPG + row) * DIN + colc] = *(const us8*)&Cs[row * 128 + colc];
    }
}

// ---------------------------------------------------------------------------
// z-GEMM: C = A@Wt^T + bias (bf16 out), fused fp32 BN partials, async staging.
#define BM 128
#define BN 128
#define BK 32
__global__ __launch_bounds__(256) void gemm_mfma(const ushortt* __restrict__ A,
                                                 const ushortt* __restrict__ Wt,
                                                 const float* __restrict__ bias,
                                                 ushortt* __restrict__ C,
                                                 float* __restrict__ psum,
                                                 float* __restrict__ psumsq,
                                                 int M, int N, int K) {
    __shared__ ushortt As[BM * BK];
    __shared__ ushortt Bs[BN * BK];
    __shared__ ushortt Cs[BM * BN];
    __shared__ float redS[2][BN];
    __shared__ float redQ[2][BN];
    const int tid  = threadIdx.x;
    const int wave = tid >> 6;
    const int lane = tid & 63;
    const int qd = lane >> 4;
    const int r  = lane & 15;
    const int wm = (wave >> 1) * 64;
    const int wn = (wave & 1) * 64;
    const int m0 = blockIdx.y * BM;
    const int n0 = blockIdx.x * BN;

    f32x4 acc[4][4] = {};

    for (int k0 = 0; k0 < K; k0 += BK) {
#pragma unroll
        for (int s = 0; s < 2; ++s) {
            const int o   = wave * 128 + s * 64 + lane;
            const int row = o >> 2;
            const int cg  = o & 3;
            g2lds16(A  + (size_t)(m0 + row) * K + k0 + cg * 8,
                    &As[(size_t)(wave * 128 + s * 64) * 8]);
            g2lds16(Wt + (size_t)(n0 + row) * K + k0 + cg * 8,
                    &Bs[(size_t)(wave * 128 + s * 64) * 8]);
        }
        __syncthreads();
        short8 af[4], bfr[4];
#pragma unroll
        for (int i = 0; i < 4; ++i)
            af[i] = *(const short8*)&As[(wm + i * 16 + r) * BK + qd * 8];
#pragma unroll
        for (int j = 0; j < 4; ++j)
            bfr[j] = *(const short8*)&Bs[(wn + j * 16 + r) * BK + qd * 8];
#pragma unroll
        for (int i = 0; i < 4; ++i)
#pragma unroll
            for (int j = 0; j < 4; ++j)
                acc[i][j] = __builtin_amdgcn_mfma_f32_16x16x32_bf16(af[i], bfr[j], acc[i][j], 0, 0, 0);
        __syncthreads();
    }

#pragma unroll
    for (int j = 0; j < 4; ++j) {
        const int coll = wn + j * 16 + r;
        const float bv = bias[n0 + coll];
        float s = 0.0f, q = 0.0f;
#pragma unroll
        for (int i = 0; i < 4; ++i)
#pragma unroll
            for (int t = 0; t < 4; ++t) {
                const float v = acc[i][j][t] + bv;
                Cs[(wm + i * 16 + qd * 4 + t) * BN + coll] = f2bf(v);
                s += v;
                q = fmaf(v, v, q);
            }
        s += __shfl_xor(s, 16); s += __shfl_xor(s, 32);
        q += __shfl_xor(q, 16); q += __shfl_xor(q, 32);
        if (qd == 0) {
            redS[wave >> 1][coll] = s;
            redQ[wave >> 1][coll] = q;
        }
    }
    __syncthreads();
    if (tid < BN) {
        psum[(size_t)blockIdx.y * N + n0 + tid]   = redS[0][tid] + redS[1][tid];
        psumsq[(size_t)blockIdx.y * N + n0 + tid] = redQ[0][tid] + redQ[1][tid];
    }
#pragma unroll
    for (int s8 = 0; s8 < 8; ++s8) {
        const int c    = tid + 256 * s8;
        const int row  = c >> 4;
        const int colc = (c & 15) * 8;
        const us8 v = *(const us8*)&Cs[row * BN + colc];
        *(us8*)&C[(size_t)(m0 + row) * N + n0 + colc] = v;
    }
}

// ---------------------------------------------------------------------------
__global__ __launch_bounds__(256) void bn_finalize(const float* __restrict__ psum,
                                                   const float* __restrict__ psumsq,
                                                   const float* __restrict__ g,
                                                   const float* __restrict__ be,
                                                   int ncols,
                                                   float* __restrict__ scale,
                                                   float* __restrict__ shift) {
    const int c = blockIdx.x * 256 + threadIdx.x;
    double s = 0.0, s2 = 0.0;
    for (int k = 0; k < NCHUNK; ++k) {
        s += (double)psum[(size_t)k * ncols + c];
        s2 += (double)psumsq[(size_t)k * ncols + c];
    }
    const double mean = s / (double)NTOT;
    const double var = s2 / (double)NTOT - mean * mean;
    const double rs = 1.0 / sqrt(var + 1e-5);
    const float sc = (float)((double)g[c] * rs);
    scale[c] = sc;
    shift[c] = (float)((double)be[c] - mean * (double)sc);
}

// ---------------------------------------------------------------------------
// h-GEMM: C = relu(BN(A))@Wt^T + bias, scale/shift precomputed, + fp32 stats.
__global__ __launch_bounds__(256) void gemm_bn(const ushortt* __restrict__ A,
                                               const ushortt* __restrict__ Wt,
                                               const float* __restrict__ scale,
                                               const float* __restrict__ shift,
                                               const float* __restrict__ bias,
                                               ushortt* __restrict__ C,
                                               float* __restrict__ psOut,
                                               float* __restrict__ pqOut) {
    __shared__ ushortt As[BM * BK];
    __shared__ ushortt Bs[BN * BK];
    __shared__ ushortt Cs[BM * BN];
    __shared__ float redS[2][BN];
    __shared__ float redQ[2][BN];
    __shared__ float scs[DD2], shs[DD2];
    const int tid  = threadIdx.x;
    const int wave = tid >> 6;
    const int lane = tid & 63;
    const int qd = lane >> 4;
    const int r  = lane & 15;
    const int wm = (wave >> 1) * 64;
    const int wn = (wave & 1) * 64;
    const int m0 = blockIdx.y * BM;
    const int n0 = blockIdx.x * BN;
    const int K = DD2, N = DD;

    for (int i = tid; i < K; i += 256) {
        scs[i] = scale[i];
        shs[i] = shift[i];
    }
    __syncthreads();

    f32x4 acc[4][4] = {};

    for (int k0 = 0; k0 < K; k0 += BK) {
#pragma unroll
        for (int s = 0; s < 2; ++s) {
            const int o   = wave * 128 + s * 64 + lane;
            const int row = o >> 2;
            const int cg  = o & 3;
            g2lds16(Wt + (size_t)(n0 + row) * K + k0 + cg * 8,
                    &Bs[(size_t)(wave * 128 + s * 64) * 8]);
        }
#pragma unroll
        for (int s = 0; s < 2; ++s) {
            const int o   = wave * 128 + s * 64 + lane;
            const int row = o >> 2;
            const int cg  = o & 3;
            const us8 a8 = *(const us8*)&A[(size_t)(m0 + row) * K + k0 + cg * 8];
            const float4 s4a = *(const float4*)&scs[k0 + cg * 8];
            const float4 s4b = *(const float4*)&scs[k0 + cg * 8 + 4];
            const float4 h4a = *(const float4*)&shs[k0 + cg * 8];
            const float4 h4b = *(const float4*)&shs[k0 + cg * 8 + 4];
            us8 t8;
            t8[0] = f2bf(fmaxf(fmaf(bf2f(a8[0]), s4a.x, h4a.x), 0.0f));
            t8[1] = f2bf(fmaxf(fmaf(bf2f(a8[1]), s4a.y, h4a.y), 0.0f));
            t8[2] = f2bf(fmaxf(fmaf(bf2f(a8[2]), s4a.z, h4a.z), 0.0f));
            t8[3] = f2bf(fmaxf(fmaf(bf2f(a8[3]), s4a.w, h4a.w), 0.0f));
            t8[4] = f2bf(fmaxf(fmaf(bf2f(a8[4]), s4b.x, h4b.x), 0.0f));
            t8[5] = f2bf(fmaxf(fmaf(bf2f(a8[5]), s4b.y, h4b.y), 0.0f));
            t8[6] = f2bf(fmaxf(fmaf(bf2f(a8[6]), s4b.z, h4b.z), 0.0f));
            t8[7] = f2bf(fmaxf(fmaf(bf2f(a8[7]), s4b.w, h4b.w), 0.0f));
            *(us8*)&As[row * BK + cg * 8] = t8;
        }
        __syncthreads();
        short8 af[4], bfr[4];
#pragma unroll
        for (int i = 0; i < 4; ++i)
            af[i] = *(const short8*)&As[(wm + i * 16 + r) * BK + qd * 8];
#pragma unroll
        for (int j = 0; j < 4; ++j)
            bfr[j] = *(const short8*)&Bs[(wn + j * 16 + r) * BK + qd * 8];
#pragma unroll
        for (int i = 0; i < 4; ++i)
#pragma unroll
            for (int j = 0; j < 4; ++j)
                acc[i][j] = __builtin_amdgcn_mfma_f32_16x16x32_bf16(af[i], bfr[j], acc[i][j], 0, 0, 0);
        __syncthreads();
    }

#pragma unroll
    for (int j = 0; j < 4; ++j) {
        const int coll = wn + j * 16 + r;
        const float bv = bias[n0 + coll];
        float s = 0.0f, q = 0.0f;
#pragma unroll
        for (int i = 0; i < 4; ++i)
#pragma unroll
            for (int t = 0; t < 4; ++t) {
                const float v = acc[i][j][t] + bv;
                Cs[(wm + i * 16 + qd * 4 + t) * BN + coll] = f2bf(v);
                s += v;
                q = fmaf(v, v, q);
            }
        s += __shfl_xor(s, 16); s += __shfl_xor(s, 32);
        q += __shfl_xor(q, 16); q += __shfl_xor(q, 32);
        if (qd == 0) {
            redS[wave >> 1][coll] = s;
            redQ[wave >> 1][coll] = q;
        }
    }
    __syncthreads();
    if (tid < BN) {
        psOut[(size_t)blockIdx.y * N + n0 + tid] = redS[0][tid] + redS[1][tid];
        pqOut[(size_t)blockIdx.y * N + n0 + tid] = redQ[0][tid] + redQ[1][tid];
    }
#pragma unroll
    for (int s8 = 0; s8 < 8; ++s8) {
        const int c    = tid + 256 * s8;
        const int row  = c >> 4;
        const int colc = (c & 15) * 8;
        const us8 v = *(const us8*)&Cs[row * BN + colc];
        *(us8*)&C[(size_t)(m0 + row) * N + n0 + colc] = v;
    }
}

// ---------------------------------------------------------------------------
// agg2: fused finalize(g1) for this block's 128 cols + post staging
// (chunked, conflict-light) + s2 = M @ post via MFMA. Grid (2, BGR).
__global__ __launch_bounds__(256) void agg2_mm(const ushortt* __restrict__ h,
                                               const float* __restrict__ psum,
                                               const float* __restrict__ psumsq,
                                               const float* __restrict__ g,
                                               const float* __restrict__ be,
                                               const float* __restrict__ vemb,
                                               const ushortt* __restrict__ Madj,
                                               ushortt* __restrict__ s2) {
    __shared__ ushortt Ms[NPG * MP];
    __shared__ ushortt PT[NPG * MP];
    __shared__ double redS[2][128];
    __shared__ double redQ[2][128];
    __shared__ float scs[128], shs[128];
    const int nb = blockIdx.x, b = blockIdx.y, t = threadIdx.x;
    const int wave = t >> 6, lane = t & 63;
    const int qd = lane >> 4, r = lane & 15;
    const int wm = (wave >> 1) * 64, wn = (wave & 1) * 64;
    const ushortt* Mg = Madj + (size_t)b * NPG * NPG;
#pragma unroll
    for (int k = 0; k < 8; ++k) {
        const int ch = t + k * 256;
        const int m = ch >> 4, sc = (ch & 15) * 8;
        *(us8*)&Ms[m * MP + sc] = *(const us8*)&Mg[m * NPG + sc];
    }
    {
        const int cl = t & 127, half = t >> 7;
        const int c = nb * 128 + cl;
        double s = 0.0, q = 0.0;
#pragma unroll 4
        for (int k = half * 128; k < half * 128 + 128; ++k) {
            s += (double)psum[(size_t)k * DD + c];
            q += (double)psumsq[(size_t)k * DD + c];
        }
        redS[half][cl] = s;
        redQ[half][cl] = q;
    }
    __syncthreads();
    if (t < 128) {
        const int c = nb * 128 + t;
        const double s = redS[0][t] + redS[1][t];
        const double q = redQ[0][t] + redQ[1][t];
        const double mean = s / (double)NTOT;
        const double var = q / (double)NTOT - mean * mean;
        const double rs = 1.0 / sqrt(var + 1e-5);
        const float sc = (float)((double)g[c] * rs);
        scs[t] = sc;
        shs[t] = (float)((double)be[c] - mean * (double)sc);
    }
    __syncthreads();
#pragma unroll
    for (int k = 0; k < 8; ++k) {
        const int ch = t + k * 256;
        const int cl = ch & 127, s8 = ch >> 7;
        const float scv = scs[cl], shv = shs[cl], vev = vemb[nb * 128 + cl];
        us8 o;
#pragma unroll
        for (int j = 0; j < 8; ++j) {
            float v = fmaf(bf2f(h[(size_t)(b * NPG + s8 * 8 + j) * DD + nb * 128 + cl]), scv, shv);
            o[j] = f2bf(fmaxf(v, 0.0f) + vev);
        }
        *(us8*)&PT[cl * MP + s8 * 8] = o;
    }
    __syncthreads();
    f32x4 acc[4][4] = {};
#pragma unroll
    for (int ks = 0; ks < 4; ++ks) {
        const int k0 = ks * 32 + qd * 8;
        short8 af[4], bfr[4];
#pragma unroll
        for (int i = 0; i < 4; ++i)
            af[i] = *(const short8*)&Ms[(wm + i * 16 + r) * MP + k0];
#pragma unroll
        for (int j = 0; j < 4; ++j)
            bfr[j] = *(const short8*)&PT[(wn + j * 16 + r) * MP + k0];
#pragma unroll
        for (int i = 0; i < 4; ++i)
#pragma unroll
            for (int j = 0; j < 4; ++j)
                acc[i][j] = __builtin_amdgcn_mfma_f32_16x16x32_bf16(af[i], bfr[j], acc[i][j], 0, 0, 0);
    }
    __syncthreads();
    ushortt* Cs = Ms;
#pragma unroll
    for (int j = 0; j < 4; ++j) {
        const int coll = wn + j * 16 + r;
#pragma unroll
        for (int i = 0; i < 4; ++i)
#pragma unroll
            for (int tt = 0; tt < 4; ++tt)
                Cs[(wm + i * 16 + qd * 4 + tt) * 128 + coll] = f2bf(acc[i][j][tt]);
    }
    __syncthreads();
#pragma unroll
    for (int k = 0; k < 8; ++k) {
        const int ch = t + k * 256;
        const int row = ch >> 4, colc = (ch & 15) * 8;
        *(us8*)&s2[(size_t)(b * NPG + row) * DD + nb * 128 + colc] =
            *(const us8*)&Cs[row * 128 + colc];
    }
}

// ---------------------------------------------------------------------------
// Mega tail: per-graph block (512 thr). Fused finalize(g2,be2) -> node dots
// -> edge scores -> stable descending rank-sort -> output writes.
__global__ __launch_bounds__(EPG) void sort_mega(const ushortt* __restrict__ h2,
                                                 const float* __restrict__ psum,
                                                 const float* __restrict__ psumsq,
                                                 const float* __restrict__ g,
                                                 const float* __restrict__ be,
                                                 const float* __restrict__ Wl,
                                                 const float* __restrict__ bl,
                                                 const int* __restrict__ ei,
                                                 float* __restrict__ out) {
    __shared__ double redS[2][DD];
    __shared__ double redQ[2][DD];
    __shared__ float scs[DD], shs[DD];
    __shared__ float pa[NPG], pb[NPG];
    __shared__ float pw[EPG];
    __shared__ int ord[EPG];
    const int b = blockIdx.x, t = threadIdx.x;
    {
        const int c = t & 255, half = t >> 8;
        double s = 0.0, q = 0.0;
#pragma unroll 4
        for (int k = half * 128; k < half * 128 + 128; ++k) {
            s += (double)psum[(size_t)k * DD + c];
            q += (double)psumsq[(size_t)k * DD + c];
        }
        redS[half][c] = s;
        redQ[half][c] = q;
    }
    __syncthreads();
    if (t < DD) {
        const double s = redS[0][t] + redS[1][t];
        const double q = redQ[0][t] + redQ[1][t];
        const double mean = s / (double)NTOT;
        const double var = q / (double)NTOT - mean * mean;
        const double rs = 1.0 / sqrt(var + 1e-5);
        const float sc = (float)((double)g[t] * rs);
        scs[t] = sc;
        shs[t] = (float)((double)be[t] - mean * (double)sc);
    }
    __syncthreads();
    {
        const int wave = t >> 6, lane = t & 63;
        const float4 w0 = *(const float4*)&Wl[lane * 4];
        const float4 w1 = *(const float4*)&Wl[DD + lane * 4];
        const float4 sc4 = *(const float4*)&scs[lane * 4];
        const float4 sh4 = *(const float4*)&shs[lane * 4];
        for (int n = wave; n < NPG; n += 8) {
            const us4 z4 = *(const us4*)&h2[(size_t)(b * NPG + n) * DD + lane * 4];
            const float x0 = fmaf(bf2f(z4.x), sc4.x, sh4.x);
            const float x1 = fmaf(bf2f(z4.y), sc4.y, sh4.y);
            const float x2 = fmaf(bf2f(z4.z), sc4.z, sh4.z);
            const float x3 = fmaf(bf2f(z4.w), sc4.w, sh4.w);
            float sa = x0 * w0.x + x1 * w0.y + x2 * w0.z + x3 * w0.w;
            float sb = x0 * w1.x + x1 * w1.y + x2 * w1.z + x3 * w1.w;
#pragma unroll
            for (int off = 32; off >= 1; off >>= 1) {
                sa += __shfl_down(sa, off);
                sb += __shfl_down(sb, off);
            }
            if (lane == 0) { pa[n] = sa; pb[n] = sb; }
        }
    }
    __syncthreads();
    const int rl = ei[b * EPG + t] - b * NPG;
    const int cl = ei[ETOT + b * EPG + t] - b * NPG;
    const float v = pa[rl] + pb[cl] + bl[0];
    pw[t] = v;
    out[OFF_PRED + b * EPG + t] = v;
    __syncthreads();
    int rank = 0;
#pragma unroll 8
    for (int k = 0; k < EPG; ++k) {
        const float u = pw[k];
        rank += (u > v) || (u == v && k < t);
    }
    ord[rank] = t;
    __syncthreads();
    const int j = ord[t];
    const float wv = pw[j];
    const float e0 = (float)ei[b * EPG + j];
    const float e1 = (float)ei[ETOT + b * EPG + j];
    if (t < NRES) {
        out[OFF_CEI + b * NRES + t] = e0;
        out[OFF_CEI + BGR * NRES + b * NRES + t] = e1;
        out[OFF_CW + b * NRES + t] = wv;
    } else {
        const int p = t - NRES;
        out[OFF_FEI + b * NRES + p] = e0;
        out[OFF_FEI + BGR * NRES + b * NRES + p] = e1;
        out[OFF_FW + b * NRES + p] = -wv;
    }
}

// ---------------------------------------------------------------------------
extern "C" void kernel_launch(void* const* d_in, const int* in_sizes, int n_in,
                              void* d_out, int out_size, void* d_ws, size_t ws_size,
                              hipStream_t stream) {
    (void)in_sizes; (void)n_in; (void)out_size; (void)ws_size;
    const float* x    = (const float*)d_in[0];
    const int*   ei   = (const int*)d_in[1];
    const float* vemb = (const float*)d_in[3];
    const float* W1a  = (const float*)d_in[4];
    const float* b1a  = (const float*)d_in[5];
    const float* g1a  = (const float*)d_in[6];
    const float* be1a = (const float*)d_in[7];
    const float* W1b  = (const float*)d_in[8];
    const float* b1b  = (const float*)d_in[9];
    const float* g1   = (const float*)d_in[10];
    const float* be1  = (const float*)d_in[11];
    const float* W2a  = (const float*)d_in[12];
    const float* b2a  = (const float*)d_in[13];
    const float* g2a  = (const float*)d_in[14];
    const float* be2a = (const float*)d_in[15];
    const float* W2b  = (const float*)d_in[16];
    const float* b2b  = (const float*)d_in[17];
    const float* g2   = (const float*)d_in[18];
    const float* be2  = (const float*)d_in[19];
    const float* Wl   = (const float*)d_in[20];
    const float* bl   = (const float*)d_in[21];
    float* out = (float*)d_out;

    char* wp = (char*)d_ws;
    auto alloc = [&](size_t bytes) -> char* {
        char* r = wp;
        wp += (bytes + 255) & ~(size_t)255;
        return r;
    };
    ushortt* zb    = (ushortt*)alloc((size_t)NTOT * 512 * 2);  // z1 / z2
    ushortt* bufC  = (ushortt*)alloc((size_t)NTOT * 256 * 2);  // h1 / h2
    ushortt* bufS1 = (ushortt*)alloc((size_t)NTOT * 128 * 2);  // s1
    ushortt* bufS2 = (ushortt*)alloc((size_t)NTOT * 256 * 2);  // s2
    ushortt* Madj  = (ushortt*)alloc((size_t)BGR * NPG * NPG * 2);
    ushortt* Wt1a  = (ushortt*)alloc((size_t)DIN * DD2 * 2);
    ushortt* Wt1b  = (ushortt*)alloc((size_t)DD2 * DD * 2);
    ushortt* Wt2a  = (ushortt*)alloc((size_t)DD * DD2 * 2);
    ushortt* Wt2b  = (ushortt*)alloc((size_t)DD2 * DD * 2);
    float*   psA   = (float*)alloc((size_t)256 * DD2 * 4);
    float*   pqA   = (float*)alloc((size_t)256 * DD2 * 4);
    float*   psB   = (float*)alloc((size_t)256 * DD * 4);
    float*   pqB   = (float*)alloc((size_t)256 * DD * 4);
    float*   scA   = (float*)alloc(DD2 * 4);
    float*   shA   = (float*)alloc(DD2 * 4);

    // 1) weights + (adjacency -> Madj, s1) in one dispatch
    prep<<<2048, 256, 0, stream>>>(W1a, W1b, W2a, W2b, x, ei,
                                   Wt1a, Wt1b, Wt2a, Wt2b, Madj, bufS1);

    // 2) z1 = s1 @ W1a + b1a (+stats)
    gemm_mfma<<<dim3(DD2 / BN, NTOT / BM), 256, 0, stream>>>(bufS1, Wt1a, b1a, zb, psA, pqA, NTOT, DD2, DIN);
    bn_finalize<<<2, 256, 0, stream>>>(psA, pqA, g1a, be1a, DD2, scA, shA);

    // 3) h1 = relu(BN(z1)) @ W1b + b1b (+stats)
    gemm_bn<<<dim3(DD / BN, NTOT / BM), 256, 0, stream>>>(zb, Wt1b, scA, shA, b1b, bufC, psB, pqB);

    // 4) s2 = M @ (relu(BN(h1)) + vemb)  [finalize(g1) fused]
    agg2_mm<<<dim3(2, BGR), 256, 0, stream>>>(bufC, psB, pqB, g1, be1, vemb, Madj, bufS2);

    // 5) z2 = s2 @ W2a + b2a (+stats)
    gemm_mfma<<<dim3(DD2 / BN, NTOT / BM), 256, 0, stream>>>(bufS2, Wt2a, b2a, zb, psA, pqA, NTOT, DD2, DD);
    bn_finalize<<<2, 256, 0, stream>>>(psA, pqA, g2a, be2a, DD2, scA, shA);

    // 6) h2 = relu(BN(z2)) @ W2b + b2b (+stats)
    gemm_bn<<<dim3(DD / BN, NTOT / BM), 256, 0, stream>>>(zb, Wt2b, scA, shA, b2b, bufC, psB, pqB);

    // 7) mega tail (finalize(g2) fused)
    sort_mega<<<BGR, EPG, 0, stream>>>(bufC, psB, pqB, g2, be2, Wl, bl, ei, out);
}

// Round 15
// 302.214 us; speedup vs baseline: 1.7826x; 1.0152x over previous
//
#include <hip/hip_runtime.h>

// Problem constants
#define BGR   256
#define NPG   128
#define EPG   512
#define DIN   128
#define DD    256
#define DD2   512
#define NTOT  (BGR * NPG)   // 32768
#define ETOT  (BGR * EPG)   // 131072
#define NRES  (EPG / 2)
#define NCHUNK 256
#define MP    136           // padded LDS stride (ushorts)

// Output layout (floats)
#define OFF_CEI  0
#define OFF_CW   (2 * BGR * NRES)
#define OFF_FEI  (OFF_CW + BGR * NRES)
#define OFF_FW   (OFF_FEI + 2 * BGR * NRES)
#define OFF_PRED (OFF_FW + BGR * NRES)

typedef unsigned short ushortt;
typedef __attribute__((ext_vector_type(4))) unsigned short us4;
typedef __attribute__((ext_vector_type(8))) unsigned short us8;
typedef __attribute__((ext_vector_type(8))) short short8;
typedef __attribute__((ext_vector_type(4))) float f32x4;

__device__ __forceinline__ ushortt f2bf(float f) {
    unsigned int u = __float_as_uint(f);
    unsigned int r = (u + 0x7fffu + ((u >> 16) & 1u)) >> 16;
    return (ushortt)r;
}
__device__ __forceinline__ float bf2f(ushortt u) {
    return __uint_as_float(((unsigned int)u) << 16);
}

__device__ __forceinline__ void g2lds16(const void* g, void* l) {
    __builtin_amdgcn_global_load_lds(
        (const __attribute__((address_space(1))) unsigned int*)g,
        (__attribute__((address_space(3))) unsigned int*)l, 16, 0, 0);
}

// ---------------------------------------------------------------------------
// prep: blocks 0..1791 transpose weights to bf16 [N][K]; blocks 1792..2047
// build per-graph adjacency (I + A^T), write Madj, and compute
// s1 = bf16(M @ bf16(x)) via MFMA entirely in LDS.   (unchanged from R10)
__global__ __launch_bounds__(256) void prep(const float* __restrict__ W1a,
                                            const float* __restrict__ W1b,
                                            const float* __restrict__ W2a,
                                            const float* __restrict__ W2b,
                                            const float* __restrict__ x,
                                            const int* __restrict__ ei,
                                            ushortt* __restrict__ Wt1a,
                                            ushortt* __restrict__ Wt1b,
                                            ushortt* __restrict__ Wt2a,
                                            ushortt* __restrict__ Wt2b,
                                            ushortt* __restrict__ Madj,
                                            ushortt* __restrict__ s1) {
    __shared__ __align__(16) char smem[102400];
    const int t = threadIdx.x;
    if (blockIdx.x < 1792) {
        const int idx = blockIdx.x * 256 + t;
        if (idx < 65536) {                       // W1a: 128x512
            const int k = idx >> 9, n = idx & 511;
            Wt1a[n * DIN + k] = f2bf(W1a[idx]);
        } else if (idx < 196608) {               // W1b: 512x256
            const int i = idx - 65536;
            const int k = i >> 8, n = i & 255;
            Wt1b[n * DD2 + k] = f2bf(W1b[i]);
        } else if (idx < 327680) {               // W2a: 256x512
            const int i = idx - 196608;
            const int k = i >> 9, n = i & 511;
            Wt2a[n * DD + k] = f2bf(W2a[i]);
        } else if (idx < 458752) {               // W2b: 512x256
            const int i = idx - 327680;
            const int k = i >> 8, n = i & 255;
            Wt2b[n * DD2 + k] = f2bf(W2b[i]);
        }
        return;
    }
    const int b = blockIdx.x - 1792;
    ushortt* Ms = (ushortt*)smem;                    // [128][136]
    int* cnt = (int*)(smem + 34816);                 // 64 KB
    ushortt* XT = (ushortt*)(smem + 34816);          // [128][136], after cnt dead
    ushortt* Cs = (ushortt*)(smem + 69632);          // [128][128]
    const int wave = t >> 6, lane = t & 63;
    const int qd = lane >> 4, r = lane & 15;
    const int wm = (wave >> 1) * 64, wn = (wave & 1) * 64;

    for (int i = t; i < NPG * NPG; i += 256) cnt[i] = 0;
    __syncthreads();
    for (int e = t; e < EPG; e += 256) {
        const int src = ei[b * EPG + e] - b * NPG;
        const int dst = ei[ETOT + b * EPG + e] - b * NPG;
        atomicAdd(&cnt[dst * NPG + src], 1);
    }
    __syncthreads();
#pragma unroll
    for (int k = 0; k < 8; ++k) {
        const int ch = t + k * 256;
        const int m = ch >> 4, sc = (ch & 15) * 8;
        us8 o;
#pragma unroll
        for (int e = 0; e < 8; ++e)
            o[e] = f2bf((float)(cnt[m * NPG + sc + e] + (m == sc + e ? 1 : 0)));
        *(us8*)&Ms[m * MP + sc] = o;
        *(us8*)&Madj[(size_t)b * NPG * NPG + m * NPG + sc] = o;
    }
    __syncthreads();

#pragma unroll
    for (int k = 0; k < 8; ++k) {
        const int ch = t + k * 256;
        const int c = ch & 127, s8 = ch >> 7;
        us8 o;
#pragma unroll
        for (int j = 0; j < 8; ++j)
            o[j] = f2bf(x[(size_t)(b * NPG + s8 * 8 + j) * DIN + c]);
        *(us8*)&XT[c * MP + s8 * 8] = o;
    }
    __syncthreads();

    f32x4 acc[4][4] = {};
#pragma unroll
    for (int ks = 0; ks < 4; ++ks) {
        const int k0 = ks * 32 + qd * 8;
        short8 af[4], bfr[4];
#pragma unroll
        for (int i = 0; i < 4; ++i)
            af[i] = *(const short8*)&Ms[(wm + i * 16 + r) * MP + k0];
#pragma unroll
        for (int j = 0; j < 4; ++j)
            bfr[j] = *(const short8*)&XT[(wn + j * 16 + r) * MP + k0];
#pragma unroll
        for (int i = 0; i < 4; ++i)
#pragma unroll
            for (int j = 0; j < 4; ++j)
                acc[i][j] = __builtin_amdgcn_mfma_f32_16x16x32_bf16(af[i], bfr[j], acc[i][j], 0, 0, 0);
    }
#pragma unroll
    for (int j = 0; j < 4; ++j) {
        const int coll = wn + j * 16 + r;
#pragma unroll
        for (int i = 0; i < 4; ++i)
#pragma unroll
            for (int tt = 0; tt < 4; ++tt)
                Cs[(wm + i * 16 + qd * 4 + tt) * 128 + coll] = f2bf(acc[i][j][tt]);
    }
    __syncthreads();
#pragma unroll
    for (int k = 0; k < 8; ++k) {
        const int ch = t + k * 256;
        const int row = ch >> 4, colc = (ch & 15) * 8;
        *(us8*)&s1[(size_t)(b * NPG + row) * DIN + colc] = *(const us8*)&Cs[row * 128 + colc];
    }
}

// ---------------------------------------------------------------------------
// z-GEMM: C = A@Wt^T + bias (bf16 out), fused fp32 BN partials.
// Batched staging: 4 BK=32 chunks async-loaded per barrier (2 barriers per
// 128-wide K-slab instead of 8) — targets the vmcnt(0) barrier drain.
#define BM 128
#define BN 128
#define BK 32
__global__ __launch_bounds__(256) void gemm_mfma(const ushortt* __restrict__ A,
                                                 const ushortt* __restrict__ Wt,
                                                 const float* __restrict__ bias,
                                                 ushortt* __restrict__ C,
                                                 float* __restrict__ psum,
                                                 float* __restrict__ psumsq,
                                                 int M, int N, int K) {
    __shared__ __align__(16) ushortt AsB[2][4][BM * BK];   // 64 KB
    __shared__ float redS[2][BN];
    __shared__ float redQ[2][BN];
    const int tid  = threadIdx.x;
    const int wave = tid >> 6;
    const int lane = tid & 63;
    const int qd = lane >> 4;
    const int r  = lane & 15;
    const int wm = (wave >> 1) * 64;
    const int wn = (wave & 1) * 64;
    const int m0 = blockIdx.y * BM;
    const int n0 = blockIdx.x * BN;

    f32x4 acc[4][4] = {};

    for (int kb = 0; kb < K; kb += 128) {
        if (kb) __syncthreads();   // prior MFMA reads complete before restage
#pragma unroll
        for (int c4 = 0; c4 < 4; ++c4) {
            const int k0 = kb + c4 * 32;
#pragma unroll
            for (int s = 0; s < 2; ++s) {
                const int o   = wave * 128 + s * 64 + lane;
                const int row = o >> 2;
                const int cg  = o & 3;
                g2lds16(A  + (size_t)(m0 + row) * K + k0 + cg * 8,
                        &AsB[0][c4][(size_t)(wave * 128 + s * 64) * 8]);
                g2lds16(Wt + (size_t)(n0 + row) * K + k0 + cg * 8,
                        &AsB[1][c4][(size_t)(wave * 128 + s * 64) * 8]);
            }
        }
        __syncthreads();
#pragma unroll
        for (int c4 = 0; c4 < 4; ++c4) {
            short8 af[4], bfr[4];
#pragma unroll
            for (int i = 0; i < 4; ++i)
                af[i] = *(const short8*)&AsB[0][c4][(wm + i * 16 + r) * BK + qd * 8];
#pragma unroll
            for (int j = 0; j < 4; ++j)
                bfr[j] = *(const short8*)&AsB[1][c4][(wn + j * 16 + r) * BK + qd * 8];
#pragma unroll
            for (int i = 0; i < 4; ++i)
#pragma unroll
                for (int j = 0; j < 4; ++j)
                    acc[i][j] = __builtin_amdgcn_mfma_f32_16x16x32_bf16(af[i], bfr[j], acc[i][j], 0, 0, 0);
        }
    }
    __syncthreads();   // MFMA reads done before Cs alias

    ushortt* Cs = &AsB[0][0][0];   // 32 KB alias over the A buffers
#pragma unroll
    for (int j = 0; j < 4; ++j) {
        const int coll = wn + j * 16 + r;
        const float bv = bias[n0 + coll];
        float s = 0.0f, q = 0.0f;
#pragma unroll
        for (int i = 0; i < 4; ++i)
#pragma unroll
            for (int t = 0; t < 4; ++t) {
                const float v = acc[i][j][t] + bv;
                Cs[(wm + i * 16 + qd * 4 + t) * BN + coll] = f2bf(v);
                s += v;
                q = fmaf(v, v, q);
            }
        s += __shfl_xor(s, 16); s += __shfl_xor(s, 32);
        q += __shfl_xor(q, 16); q += __shfl_xor(q, 32);
        if (qd == 0) {
            redS[wave >> 1][coll] = s;
            redQ[wave >> 1][coll] = q;
        }
    }
    __syncthreads();
    if (tid < BN) {
        psum[(size_t)blockIdx.y * N + n0 + tid]   = redS[0][tid] + redS[1][tid];
        psumsq[(size_t)blockIdx.y * N + n0 + tid] = redQ[0][tid] + redQ[1][tid];
    }
#pragma unroll
    for (int s8 = 0; s8 < 8; ++s8) {
        const int c    = tid + 256 * s8;
        const int row  = c >> 4;
        const int colc = (c & 15) * 8;
        const us8 v = *(const us8*)&Cs[row * BN + colc];
        *(us8*)&C[(size_t)(m0 + row) * N + n0 + colc] = v;
    }
}

// ---------------------------------------------------------------------------
__global__ __launch_bounds__(256) void bn_finalize(const float* __restrict__ psum,
                                                   const float* __restrict__ psumsq,
                                                   const float* __restrict__ g,
                                                   const float* __restrict__ be,
                                                   int ncols,
                                                   float* __restrict__ scale,
                                                   float* __restrict__ shift) {
    const int c = blockIdx.x * 256 + threadIdx.x;
    double s = 0.0, s2 = 0.0;
    for (int k = 0; k < NCHUNK; ++k) {
        s += (double)psum[(size_t)k * ncols + c];
        s2 += (double)psumsq[(size_t)k * ncols + c];
    }
    const double mean = s / (double)NTOT;
    const double var = s2 / (double)NTOT - mean * mean;
    const double rs = 1.0 / sqrt(var + 1e-5);
    const float sc = (float)((double)g[c] * rs);
    scale[c] = sc;
    shift[c] = (float)((double)be[c] - mean * (double)sc);
}

// ---------------------------------------------------------------------------
// h-GEMM: C = relu(BN(A))@Wt^T + bias, scale/shift precomputed, + fp32 stats.
// Same 4-chunk batched staging: 8 barriers over K=512 instead of 32.
__global__ __launch_bounds__(256) void gemm_bn(const ushortt* __restrict__ A,
                                               const ushortt* __restrict__ Wt,
                                               const float* __restrict__ scale,
                                               const float* __restrict__ shift,
                                               const float* __restrict__ bias,
                                               ushortt* __restrict__ C,
                                               float* __restrict__ psOut,
                                               float* __restrict__ pqOut) {
    __shared__ __align__(16) ushortt AsB[2][4][BM * BK];   // 64 KB
    __shared__ float redS[2][BN];
    __shared__ float redQ[2][BN];
    __shared__ float scs[DD2], shs[DD2];
    const int tid  = threadIdx.x;
    const int wave = tid >> 6;
    const int lane = tid & 63;
    const int qd = lane >> 4;
    const int r  = lane & 15;
    const int wm = (wave >> 1) * 64;
    const int wn = (wave & 1) * 64;
    const int m0 = blockIdx.y * BM;
    const int n0 = blockIdx.x * BN;
    const int K = DD2, N = DD;

    for (int i = tid; i < K; i += 256) {
        scs[i] = scale[i];
        shs[i] = shift[i];
    }
    __syncthreads();

    f32x4 acc[4][4] = {};

    for (int kb = 0; kb < K; kb += 128) {
        if (kb) __syncthreads();
        // B: async direct-to-LDS for all 4 chunks
#pragma unroll
        for (int c4 = 0; c4 < 4; ++c4) {
            const int k0 = kb + c4 * 32;
#pragma unroll
            for (int s = 0; s < 2; ++s) {
                const int o   = wave * 128 + s * 64 + lane;
                const int row = o >> 2;
                const int cg  = o & 3;
                g2lds16(Wt + (size_t)(n0 + row) * K + k0 + cg * 8,
                        &AsB[1][c4][(size_t)(wave * 128 + s * 64) * 8]);
            }
        }
        // A: register staging + fused BN-apply + ReLU for all 4 chunks
#pragma unroll
        for (int c4 = 0; c4 < 4; ++c4) {
            const int k0 = kb + c4 * 32;
#pragma unroll
            for (int s = 0; s < 2; ++s) {
                const int o   = wave * 128 + s * 64 + lane;
                const int row = o >> 2;
                const int cg  = o & 3;
                const us8 a8 = *(const us8*)&A[(size_t)(m0 + row) * K + k0 + cg * 8];
                const float4 s4a = *(const float4*)&scs[k0 + cg * 8];
                const float4 s4b = *(const float4*)&scs[k0 + cg * 8 + 4];
                const float4 h4a = *(const float4*)&shs[k0 + cg * 8];
                const float4 h4b = *(const float4*)&shs[k0 + cg * 8 + 4];
                us8 t8;
                t8[0] = f2bf(fmaxf(fmaf(bf2f(a8[0]), s4a.x, h4a.x), 0.0f));
                t8[1] = f2bf(fmaxf(fmaf(bf2f(a8[1]), s4a.y, h4a.y), 0.0f));
                t8[2] = f2bf(fmaxf(fmaf(bf2f(a8[2]), s4a.z, h4a.z), 0.0f));
                t8[3] = f2bf(fmaxf(fmaf(bf2f(a8[3]), s4a.w, h4a.w), 0.0f));
                t8[4] = f2bf(fmaxf(fmaf(bf2f(a8[4]), s4b.x, h4b.x), 0.0f));
                t8[5] = f2bf(fmaxf(fmaf(bf2f(a8[5]), s4b.y, h4b.y), 0.0f));
                t8[6] = f2bf(fmaxf(fmaf(bf2f(a8[6]), s4b.z, h4b.z), 0.0f));
                t8[7] = f2bf(fmaxf(fmaf(bf2f(a8[7]), s4b.w, h4b.w), 0.0f));
                *(us8*)&AsB[0][c4][row * BK + cg * 8] = t8;
            }
        }
        __syncthreads();
#pragma unroll
        for (int c4 = 0; c4 < 4; ++c4) {
            short8 af[4], bfr[4];
#pragma unroll
            for (int i = 0; i < 4; ++i)
                af[i] = *(const short8*)&AsB[0][c4][(wm + i * 16 + r) * BK + qd * 8];
#pragma unroll
            for (int j = 0; j < 4; ++j)
                bfr[j] = *(const short8*)&AsB[1][c4][(wn + j * 16 + r) * BK + qd * 8];
#pragma unroll
            for (int i = 0; i < 4; ++i)
#pragma unroll
                for (int j = 0; j < 4; ++j)
                    acc[i][j] = __builtin_amdgcn_mfma_f32_16x16x32_bf16(af[i], bfr[j], acc[i][j], 0, 0, 0);
        }
    }
    __syncthreads();

    ushortt* Cs = &AsB[0][0][0];
#pragma unroll
    for (int j = 0; j < 4; ++j) {
        const int coll = wn + j * 16 + r;
        const float bv = bias[n0 + coll];
        float s = 0.0f, q = 0.0f;
#pragma unroll
        for (int i = 0; i < 4; ++i)
#pragma unroll
            for (int t = 0; t < 4; ++t) {
                const float v = acc[i][j][t] + bv;
                Cs[(wm + i * 16 + qd * 4 + t) * BN + coll] = f2bf(v);
                s += v;
                q = fmaf(v, v, q);
            }
        s += __shfl_xor(s, 16); s += __shfl_xor(s, 32);
        q += __shfl_xor(q, 16); q += __shfl_xor(q, 32);
        if (qd == 0) {
            redS[wave >> 1][coll] = s;
            redQ[wave >> 1][coll] = q;
        }
    }
    __syncthreads();
    if (tid < BN) {
        psOut[(size_t)blockIdx.y * N + n0 + tid] = redS[0][tid] + redS[1][tid];
        pqOut[(size_t)blockIdx.y * N + n0 + tid] = redQ[0][tid] + redQ[1][tid];
    }
#pragma unroll
    for (int s8 = 0; s8 < 8; ++s8) {
        const int c    = tid + 256 * s8;
        const int row  = c >> 4;
        const int colc = (c & 15) * 8;
        const us8 v = *(const us8*)&Cs[row * BN + colc];
        *(us8*)&C[(size_t)(m0 + row) * N + n0 + colc] = v;
    }
}

// ---------------------------------------------------------------------------
// agg2: fused finalize(g1) + post staging + s2 = M @ post. (unchanged)
__global__ __launch_bounds__(256) void agg2_mm(const ushortt* __restrict__ h,
                                               const float* __restrict__ psum,
                                               const float* __restrict__ psumsq,
                                               const float* __restrict__ g,
                                               const float* __restrict__ be,
                                               const float* __restrict__ vemb,
                                               const ushortt* __restrict__ Madj,
                                               ushortt* __restrict__ s2) {
    __shared__ ushortt Ms[NPG * MP];
    __shared__ ushortt PT[NPG * MP];
    __shared__ double redS[2][128];
    __shared__ double redQ[2][128];
    __shared__ float scs[128], shs[128];
    const int nb = blockIdx.x, b = blockIdx.y, t = threadIdx.x;
    const int wave = t >> 6, lane = t & 63;
    const int qd = lane >> 4, r = lane & 15;
    const int wm = (wave >> 1) * 64, wn = (wave & 1) * 64;
    const ushortt* Mg = Madj + (size_t)b * NPG * NPG;
#pragma unroll
    for (int k = 0; k < 8; ++k) {
        const int ch = t + k * 256;
        const int m = ch >> 4, sc = (ch & 15) * 8;
        *(us8*)&Ms[m * MP + sc] = *(const us8*)&Mg[m * NPG + sc];
    }
    {
        const int cl = t & 127, half = t >> 7;
        const int c = nb * 128 + cl;
        double s = 0.0, q = 0.0;
#pragma unroll 4
        for (int k = half * 128; k < half * 128 + 128; ++k) {
            s += (double)psum[(size_t)k * DD + c];
            q += (double)psumsq[(size_t)k * DD + c];
        }
        redS[half][cl] = s;
        redQ[half][cl] = q;
    }
    __syncthreads();
    if (t < 128) {
        const int c = nb * 128 + t;
        const double s = redS[0][t] + redS[1][t];
        const double q = redQ[0][t] + redQ[1][t];
        const double mean = s / (double)NTOT;
        const double var = q / (double)NTOT - mean * mean;
        const double rs = 1.0 / sqrt(var + 1e-5);
        const float sc = (float)((double)g[c] * rs);
        scs[t] = sc;
        shs[t] = (float)((double)be[c] - mean * (double)sc);
    }
    __syncthreads();
#pragma unroll
    for (int k = 0; k < 8; ++k) {
        const int ch = t + k * 256;
        const int cl = ch & 127, s8 = ch >> 7;
        const float scv = scs[cl], shv = shs[cl], vev = vemb[nb * 128 + cl];
        us8 o;
#pragma unroll
        for (int j = 0; j < 8; ++j) {
            float v = fmaf(bf2f(h[(size_t)(b * NPG + s8 * 8 + j) * DD + nb * 128 + cl]), scv, shv);
            o[j] = f2bf(fmaxf(v, 0.0f) + vev);
        }
        *(us8*)&PT[cl * MP + s8 * 8] = o;
    }
    __syncthreads();
    f32x4 acc[4][4] = {};
#pragma unroll
    for (int ks = 0; ks < 4; ++ks) {
        const int k0 = ks * 32 + qd * 8;
        short8 af[4], bfr[4];
#pragma unroll
        for (int i = 0; i < 4; ++i)
            af[i] = *(const short8*)&Ms[(wm + i * 16 + r) * MP + k0];
#pragma unroll
        for (int j = 0; j < 4; ++j)
            bfr[j] = *(const short8*)&PT[(wn + j * 16 + r) * MP + k0];
#pragma unroll
        for (int i = 0; i < 4; ++i)
#pragma unroll
            for (int j = 0; j < 4; ++j)
                acc[i][j] = __builtin_amdgcn_mfma_f32_16x16x32_bf16(af[i], bfr[j], acc[i][j], 0, 0, 0);
    }
    __syncthreads();
    ushortt* Cs = Ms;
#pragma unroll
    for (int j = 0; j < 4; ++j) {
        const int coll = wn + j * 16 + r;
#pragma unroll
        for (int i = 0; i < 4; ++i)
#pragma unroll
            for (int tt = 0; tt < 4; ++tt)
                Cs[(wm + i * 16 + qd * 4 + tt) * 128 + coll] = f2bf(acc[i][j][tt]);
    }
    __syncthreads();
#pragma unroll
    for (int k = 0; k < 8; ++k) {
        const int ch = t + k * 256;
        const int row = ch >> 4, colc = (ch & 15) * 8;
        *(us8*)&s2[(size_t)(b * NPG + row) * DD + nb * 128 + colc] =
            *(const us8*)&Cs[row * 128 + colc];
    }
}

// ---------------------------------------------------------------------------
// Mega tail (unchanged).
__global__ __launch_bounds__(EPG) void sort_mega(const ushortt* __restrict__ h2,
                                                 const float* __restrict__ psum,
                                                 const float* __restrict__ psumsq,
                                                 const float* __restrict__ g,
                                                 const float* __restrict__ be,
                                                 const float* __restrict__ Wl,
                                                 const float* __restrict__ bl,
                                                 const int* __restrict__ ei,
                                                 float* __restrict__ out) {
    __shared__ double redS[2][DD];
    __shared__ double redQ[2][DD];
    __shared__ float scs[DD], shs[DD];
    __shared__ float pa[NPG], pb[NPG];
    __shared__ float pw[EPG];
    __shared__ int ord[EPG];
    const int b = blockIdx.x, t = threadIdx.x;
    {
        const int c = t & 255, half = t >> 8;
        double s = 0.0, q = 0.0;
#pragma unroll 4
        for (int k = half * 128; k < half * 128 + 128; ++k) {
            s += (double)psum[(size_t)k * DD + c];
            q += (double)psumsq[(size_t)k * DD + c];
        }
        redS[half][c] = s;
        redQ[half][c] = q;
    }
    __syncthreads();
    if (t < DD) {
        const double s = redS[0][t] + redS[1][t];
        const double q = redQ[0][t] + redQ[1][t];
        const double mean = s / (double)NTOT;
        const double var = q / (double)NTOT - mean * mean;
        const double rs = 1.0 / sqrt(var + 1e-5);
        const float sc = (float)((double)g[t] * rs);
        scs[t] = sc;
        shs[t] = (float)((double)be[t] - mean * (double)sc);
    }
    __syncthreads();
    {
        const int wave = t >> 6, lane = t & 63;
        const float4 w0 = *(const float4*)&Wl[lane * 4];
        const float4 w1 = *(const float4*)&Wl[DD + lane * 4];
        const float4 sc4 = *(const float4*)&scs[lane * 4];
        const float4 sh4 = *(const float4*)&shs[lane * 4];
        for (int n = wave; n < NPG; n += 8) {
            const us4 z4 = *(const us4*)&h2[(size_t)(b * NPG + n) * DD + lane * 4];
            const float x0 = fmaf(bf2f(z4.x), sc4.x, sh4.x);
            const float x1 = fmaf(bf2f(z4.y), sc4.y, sh4.y);
            const float x2 = fmaf(bf2f(z4.z), sc4.z, sh4.z);
            const float x3 = fmaf(bf2f(z4.w), sc4.w, sh4.w);
            float sa = x0 * w0.x + x1 * w0.y + x2 * w0.z + x3 * w0.w;
            float sb = x0 * w1.x + x1 * w1.y + x2 * w1.z + x3 * w1.w;
#pragma unroll
            for (int off = 32; off >= 1; off >>= 1) {
                sa += __shfl_down(sa, off);
                sb += __shfl_down(sb, off);
            }
            if (lane == 0) { pa[n] = sa; pb[n] = sb; }
        }
    }
    __syncthreads();
    const int rl = ei[b * EPG + t] - b * NPG;
    const int cl = ei[ETOT + b * EPG + t] - b * NPG;
    const float v = pa[rl] + pb[cl] + bl[0];
    pw[t] = v;
    out[OFF_PRED + b * EPG + t] = v;
    __syncthreads();
    int rank = 0;
#pragma unroll 8
    for (int k = 0; k < EPG; ++k) {
        const float u = pw[k];
        rank += (u > v) || (u == v && k < t);
    }
    ord[rank] = t;
    __syncthreads();
    const int j = ord[t];
    const float wv = pw[j];
    const float e0 = (float)ei[b * EPG + j];
    const float e1 = (float)ei[ETOT + b * EPG + j];
    if (t < NRES) {
        out[OFF_CEI + b * NRES + t] = e0;
        out[OFF_CEI + BGR * NRES + b * NRES + t] = e1;
        out[OFF_CW + b * NRES + t] = wv;
    } else {
        const int p = t - NRES;
        out[OFF_FEI + b * NRES + p] = e0;
        out[OFF_FEI + BGR * NRES + b * NRES + p] = e1;
        out[OFF_FW + b * NRES + p] = -wv;
    }
}

// ---------------------------------------------------------------------------
extern "C" void kernel_launch(void* const* d_in, const int* in_sizes, int n_in,
                              void* d_out, int out_size, void* d_ws, size_t ws_size,
                              hipStream_t stream) {
    (void)in_sizes; (void)n_in; (void)out_size; (void)ws_size;
    const float* x    = (const float*)d_in[0];
    const int*   ei   = (const int*)d_in[1];
    const float* vemb = (const float*)d_in[3];
    const float* W1a  = (const float*)d_in[4];
    const float* b1a  = (const float*)d_in[5];
    const float* g1a  = (const float*)d_in[6];
    const float* be1a = (const float*)d_in[7];
    const float* W1b  = (const float*)d_in[8];
    const float* b1b  = (const float*)d_in[9];
    const float* g1   = (const float*)d_in[10];
    const float* be1  = (const float*)d_in[11];
    const float* W2a  = (const float*)d_in[12];
    const float* b2a  = (const float*)d_in[13];
    const float* g2a  = (const float*)d_in[14];
    const float* be2a = (const float*)d_in[15];
    const float* W2b  = (const float*)d_in[16];
    const float* b2b  = (const float*)d_in[17];
    const float* g2   = (const float*)d_in[18];
    const float* be2  = (const float*)d_in[19];
    const float* Wl   = (const float*)d_in[20];
    const float* bl   = (const float*)d_in[21];
    float* out = (float*)d_out;

    char* wp = (char*)d_ws;
    auto alloc = [&](size_t bytes) -> char* {
        char* r = wp;
        wp += (bytes + 255) & ~(size_t)255;
        return r;
    };
    ushortt* zb    = (ushortt*)alloc((size_t)NTOT * 512 * 2);  // z1 / z2
    ushortt* bufC  = (ushortt*)alloc((size_t)NTOT * 256 * 2);  // h1 / h2
    ushortt* bufS1 = (ushortt*)alloc((size_t)NTOT * 128 * 2);  // s1
    ushortt* bufS2 = (ushortt*)alloc((size_t)NTOT * 256 * 2);  // s2
    ushortt* Madj  = (ushortt*)alloc((size_t)BGR * NPG * NPG * 2);
    ushortt* Wt1a  = (ushortt*)alloc((size_t)DIN * DD2 * 2);
    ushortt* Wt1b  = (ushortt*)alloc((size_t)DD2 * DD * 2);
    ushortt* Wt2a  = (ushortt*)alloc((size_t)DD * DD2 * 2);
    ushortt* Wt2b  = (ushortt*)alloc((size_t)DD2 * DD * 2);
    float*   psA   = (float*)alloc((size_t)256 * DD2 * 4);
    float*   pqA   = (float*)alloc((size_t)256 * DD2 * 4);
    float*   psB   = (float*)alloc((size_t)256 * DD * 4);
    float*   pqB   = (float*)alloc((size_t)256 * DD * 4);
    float*   scA   = (float*)alloc(DD2 * 4);
    float*   shA   = (float*)alloc(DD2 * 4);

    // 1) weights + (adjacency -> Madj, s1) in one dispatch
    prep<<<2048, 256, 0, stream>>>(W1a, W1b, W2a, W2b, x, ei,
                                   Wt1a, Wt1b, Wt2a, Wt2b, Madj, bufS1);

    // 2) z1 = s1 @ W1a + b1a (+stats)
    gemm_mfma<<<dim3(DD2 / BN, NTOT / BM), 256, 0, stream>>>(bufS1, Wt1a, b1a, zb, psA, pqA, NTOT, DD2, DIN);
    bn_finalize<<<2, 256, 0, stream>>>(psA, pqA, g1a, be1a, DD2, scA, shA);

    // 3) h1 = relu(BN(z1)) @ W1b + b1b (+stats)
    gemm_bn<<<dim3(DD / BN, NTOT / BM), 256, 0, stream>>>(zb, Wt1b, scA, shA, b1b, bufC, psB, pqB);

    // 4) s2 = M @ (relu(BN(h1)) + vemb)  [finalize(g1) fused]
    agg2_mm<<<dim3(2, BGR), 256, 0, stream>>>(bufC, psB, pqB, g1, be1, vemb, Madj, bufS2);

    // 5) z2 = s2 @ W2a + b2a (+stats)
    gemm_mfma<<<dim3(DD2 / BN, NTOT / BM), 256, 0, stream>>>(bufS2, Wt2a, b2a, zb, psA, pqA, NTOT, DD2, DD);
    bn_finalize<<<2, 256, 0, stream>>>(psA, pqA, g2a, be2a, DD2, scA, shA);

    // 6) h2 = relu(BN(z2)) @ W2b + b2b (+stats)
    gemm_bn<<<dim3(DD / BN, NTOT / BM), 256, 0, stream>>>(zb, Wt2b, scA, shA, b2b, bufC, psB, pqB);

    // 7) mega tail (finalize(g2) fused)
    sort_mega<<<BGR, EPG, 0, stream>>>(bufC, psB, pqB, g2, be2, Wl, bl, ei, out);
}

// Round 16
// 300.644 us; speedup vs baseline: 1.7919x; 1.0052x over previous
//
#include <hip/hip_runtime.h>

// Problem constants
#define BGR   256
#define NPG   128
#define EPG   512
#define DIN   128
#define DD    256
#define DD2   512
#define NTOT  (BGR * NPG)   // 32768
#define ETOT  (BGR * EPG)   // 131072
#define NRES  (EPG / 2)
#define NCHUNK 256
#define MP    136           // padded LDS stride (ushorts)

// Output layout (floats)
#define OFF_CEI  0
#define OFF_CW   (2 * BGR * NRES)
#define OFF_FEI  (OFF_CW + BGR * NRES)
#define OFF_FW   (OFF_FEI + 2 * BGR * NRES)
#define OFF_PRED (OFF_FW + BGR * NRES)

typedef unsigned short ushortt;
typedef __attribute__((ext_vector_type(4))) unsigned short us4;
typedef __attribute__((ext_vector_type(8))) unsigned short us8;
typedef __attribute__((ext_vector_type(8))) short short8;
typedef __attribute__((ext_vector_type(4))) float f32x4;

__device__ __forceinline__ ushortt f2bf(float f) {
    unsigned int u = __float_as_uint(f);
    unsigned int r = (u + 0x7fffu + ((u >> 16) & 1u)) >> 16;
    return (ushortt)r;
}
__device__ __forceinline__ float bf2f(ushortt u) {
    return __uint_as_float(((unsigned int)u) << 16);
}

__device__ __forceinline__ void g2lds16(const void* g, void* l) {
    __builtin_amdgcn_global_load_lds(
        (const __attribute__((address_space(1))) unsigned int*)g,
        (__attribute__((address_space(3))) unsigned int*)l, 16, 0, 0);
}

// ---------------------------------------------------------------------------
// prep: blocks 0..1791 transpose weights to bf16 [N][K]; blocks 1792..2047
// build per-graph adjacency (packed u16 LDS counts) and compute
// s1 = bf16(M @ bf16(x)) via MFMA entirely in LDS. 68 KB LDS -> 2 blocks/CU.
__global__ __launch_bounds__(256) void prep(const float* __restrict__ W1a,
                                            const float* __restrict__ W1b,
                                            const float* __restrict__ W2a,
                                            const float* __restrict__ W2b,
                                            const float* __restrict__ x,
                                            const int* __restrict__ ei,
                                            ushortt* __restrict__ Wt1a,
                                            ushortt* __restrict__ Wt1b,
                                            ushortt* __restrict__ Wt2a,
                                            ushortt* __restrict__ Wt2b,
                                            ushortt* __restrict__ s1) {
    __shared__ __align__(16) char smem[69632];
    const int t = threadIdx.x;
    if (blockIdx.x < 1792) {
        const int idx = blockIdx.x * 256 + t;
        if (idx < 65536) {                       // W1a: 128x512
            const int k = idx >> 9, n = idx & 511;
            Wt1a[n * DIN + k] = f2bf(W1a[idx]);
        } else if (idx < 196608) {               // W1b: 512x256
            const int i = idx - 65536;
            const int k = i >> 8, n = i & 255;
            Wt1b[n * DD2 + k] = f2bf(W1b[i]);
        } else if (idx < 327680) {               // W2a: 256x512
            const int i = idx - 196608;
            const int k = i >> 9, n = i & 511;
            Wt2a[n * DD + k] = f2bf(W2a[i]);
        } else if (idx < 458752) {               // W2b: 512x256
            const int i = idx - 327680;
            const int k = i >> 8, n = i & 255;
            Wt2b[n * DD2 + k] = f2bf(W2b[i]);
        }
        return;
    }
    const int b = blockIdx.x - 1792;
    ushortt* Ms = (ushortt*)smem;                    // [128][136] = 34816
    int* cnt = (int*)(smem + 34816);                 // 32768 (2x u16 packed)
    ushortt* XT = (ushortt*)(smem + 34816);          // [128][136] alias
    ushortt* Cs = (ushortt*)(smem + 34816);          // [128][128] alias
    const int wave = t >> 6, lane = t & 63;
    const int qd = lane >> 4, r = lane & 15;
    const int wm = (wave >> 1) * 64, wn = (wave & 1) * 64;

    // Phase 0: packed adjacency counts (commutative exact -> deterministic)
    for (int i = t; i < NPG * NPG / 2; i += 256) cnt[i] = 0;
    __syncthreads();
    for (int e = t; e < EPG; e += 256) {
        const int src = ei[b * EPG + e] - b * NPG;
        const int dst = ei[ETOT + b * EPG + e] - b * NPG;
        const int idx = dst * NPG + src;
        atomicAdd(&cnt[idx >> 1], 1 << ((idx & 1) * 16));
    }
    __syncthreads();
    // Phase 1: cnt -> Ms (bf16, + identity)
#pragma unroll
    for (int k = 0; k < 8; ++k) {
        const int ch = t + k * 256;
        const int m = ch >> 4, sc = (ch & 15) * 8;
        us8 o;
#pragma unroll
        for (int e = 0; e < 8; ++e) {
            const int i = m * NPG + sc + e;
            const int v = ((cnt[i >> 1] >> ((i & 1) * 16)) & 0xffff) + (m == sc + e ? 1 : 0);
            o[e] = f2bf((float)v);
        }
        *(us8*)&Ms[m * MP + sc] = o;
    }
    __syncthreads();   // cnt dead

    // Phase 2: x -> XT (chunked transpose)
#pragma unroll
    for (int k = 0; k < 8; ++k) {
        const int ch = t + k * 256;
        const int c = ch & 127, s8 = ch >> 7;
        us8 o;
#pragma unroll
        for (int j = 0; j < 8; ++j)
            o[j] = f2bf(x[(size_t)(b * NPG + s8 * 8 + j) * DIN + c]);
        *(us8*)&XT[c * MP + s8 * 8] = o;
    }
    __syncthreads();

    // Phase 3: s1 = Ms @ XT^T
    f32x4 acc[4][4] = {};
#pragma unroll
    for (int ks = 0; ks < 4; ++ks) {
        const int k0 = ks * 32 + qd * 8;
        short8 af[4], bfr[4];
#pragma unroll
        for (int i = 0; i < 4; ++i)
            af[i] = *(const short8*)&Ms[(wm + i * 16 + r) * MP + k0];
#pragma unroll
        for (int j = 0; j < 4; ++j)
            bfr[j] = *(const short8*)&XT[(wn + j * 16 + r) * MP + k0];
#pragma unroll
        for (int i = 0; i < 4; ++i)
#pragma unroll
            for (int j = 0; j < 4; ++j)
                acc[i][j] = __builtin_amdgcn_mfma_f32_16x16x32_bf16(af[i], bfr[j], acc[i][j], 0, 0, 0);
    }
    __syncthreads();   // XT dead
#pragma unroll
    for (int j = 0; j < 4; ++j) {
        const int coll = wn + j * 16 + r;
#pragma unroll
        for (int i = 0; i < 4; ++i)
#pragma unroll
            for (int tt = 0; tt < 4; ++tt)
                Cs[(wm + i * 16 + qd * 4 + tt) * 128 + coll] = f2bf(acc[i][j][tt]);
    }
    __syncthreads();
#pragma unroll
    for (int k = 0; k < 8; ++k) {
        const int ch = t + k * 256;
        const int row = ch >> 4, colc = (ch & 15) * 8;
        *(us8*)&s1[(size_t)(b * NPG + row) * DIN + colc] = *(const us8*)&Cs[row * 128 + colc];
    }
}

// ---------------------------------------------------------------------------
// z-GEMM: C = A@Wt^T + bias (bf16 out), fused fp32 BN partials, batched
// 4-chunk async staging (R14 verified).
#define BM 128
#define BN 128
#define BK 32
__global__ __launch_bounds__(256) void gemm_mfma(const ushortt* __restrict__ A,
                                                 const ushortt* __restrict__ Wt,
                                                 const float* __restrict__ bias,
                                                 ushortt* __restrict__ C,
                                                 float* __restrict__ psum,
                                                 float* __restrict__ psumsq,
                                                 int M, int N, int K) {
    __shared__ __align__(16) ushortt AsB[2][4][BM * BK];   // 64 KB
    __shared__ float redS[2][BN];
    __shared__ float redQ[2][BN];
    const int tid  = threadIdx.x;
    const int wave = tid >> 6;
    const int lane = tid & 63;
    const int qd = lane >> 4;
    const int r  = lane & 15;
    const int wm = (wave >> 1) * 64;
    const int wn = (wave & 1) * 64;
    const int m0 = blockIdx.y * BM;
    const int n0 = blockIdx.x * BN;

    f32x4 acc[4][4] = {};

    for (int kb = 0; kb < K; kb += 128) {
        if (kb) __syncthreads();
#pragma unroll
        for (int c4 = 0; c4 < 4; ++c4) {
            const int k0 = kb + c4 * 32;
#pragma unroll
            for (int s = 0; s < 2; ++s) {
                const int o   = wave * 128 + s * 64 + lane;
                const int row = o >> 2;
                const int cg  = o & 3;
                g2lds16(A  + (size_t)(m0 + row) * K + k0 + cg * 8,
                        &AsB[0][c4][(size_t)(wave * 128 + s * 64) * 8]);
                g2lds16(Wt + (size_t)(n0 + row) * K + k0 + cg * 8,
                        &AsB[1][c4][(size_t)(wave * 128 + s * 64) * 8]);
            }
        }
        __syncthreads();
#pragma unroll
        for (int c4 = 0; c4 < 4; ++c4) {
            short8 af[4], bfr[4];
#pragma unroll
            for (int i = 0; i < 4; ++i)
                af[i] = *(const short8*)&AsB[0][c4][(wm + i * 16 + r) * BK + qd * 8];
#pragma unroll
            for (int j = 0; j < 4; ++j)
                bfr[j] = *(const short8*)&AsB[1][c4][(wn + j * 16 + r) * BK + qd * 8];
#pragma unroll
            for (int i = 0; i < 4; ++i)
#pragma unroll
                for (int j = 0; j < 4; ++j)
                    acc[i][j] = __builtin_amdgcn_mfma_f32_16x16x32_bf16(af[i], bfr[j], acc[i][j], 0, 0, 0);
        }
    }
    __syncthreads();

    ushortt* Cs = &AsB[0][0][0];
#pragma unroll
    for (int j = 0; j < 4; ++j) {
        const int coll = wn + j * 16 + r;
        const float bv = bias[n0 + coll];
        float s = 0.0f, q = 0.0f;
#pragma unroll
        for (int i = 0; i < 4; ++i)
#pragma unroll
            for (int t = 0; t < 4; ++t) {
                const float v = acc[i][j][t] + bv;
                Cs[(wm + i * 16 + qd * 4 + t) * BN + coll] = f2bf(v);
                s += v;
                q = fmaf(v, v, q);
            }
        s += __shfl_xor(s, 16); s += __shfl_xor(s, 32);
        q += __shfl_xor(q, 16); q += __shfl_xor(q, 32);
        if (qd == 0) {
            redS[wave >> 1][coll] = s;
            redQ[wave >> 1][coll] = q;
        }
    }
    __syncthreads();
    if (tid < BN) {
        psum[(size_t)blockIdx.y * N + n0 + tid]   = redS[0][tid] + redS[1][tid];
        psumsq[(size_t)blockIdx.y * N + n0 + tid] = redQ[0][tid] + redQ[1][tid];
    }
#pragma unroll
    for (int s8 = 0; s8 < 8; ++s8) {
        const int c    = tid + 256 * s8;
        const int row  = c >> 4;
        const int colc = (c & 15) * 8;
        const us8 v = *(const us8*)&Cs[row * BN + colc];
        *(us8*)&C[(size_t)(m0 + row) * N + n0 + colc] = v;
    }
}

// ---------------------------------------------------------------------------
__global__ __launch_bounds__(256) void bn_finalize(const float* __restrict__ psum,
                                                   const float* __restrict__ psumsq,
                                                   const float* __restrict__ g,
                                                   const float* __restrict__ be,
                                                   int ncols,
                                                   float* __restrict__ scale,
                                                   float* __restrict__ shift) {
    const int c = blockIdx.x * 256 + threadIdx.x;
    double s = 0.0, s2 = 0.0;
    for (int k = 0; k < NCHUNK; ++k) {
        s += (double)psum[(size_t)k * ncols + c];
        s2 += (double)psumsq[(size_t)k * ncols + c];
    }
    const double mean = s / (double)NTOT;
    const double var = s2 / (double)NTOT - mean * mean;
    const double rs = 1.0 / sqrt(var + 1e-5);
    const float sc = (float)((double)g[c] * rs);
    scale[c] = sc;
    shift[c] = (float)((double)be[c] - mean * (double)sc);
}

// ---------------------------------------------------------------------------
// h-GEMM: C = relu(BN(A))@Wt^T + bias, batched staging (R14 verified).
__global__ __launch_bounds__(256) void gemm_bn(const ushortt* __restrict__ A,
                                               const ushortt* __restrict__ Wt,
                                               const float* __restrict__ scale,
                                               const float* __restrict__ shift,
                                               const float* __restrict__ bias,
                                               ushortt* __restrict__ C,
                                               float* __restrict__ psOut,
                                               float* __restrict__ pqOut) {
    __shared__ __align__(16) ushortt AsB[2][4][BM * BK];   // 64 KB
    __shared__ float redS[2][BN];
    __shared__ float redQ[2][BN];
    __shared__ float scs[DD2], shs[DD2];
    const int tid  = threadIdx.x;
    const int wave = tid >> 6;
    const int lane = tid & 63;
    const int qd = lane >> 4;
    const int r  = lane & 15;
    const int wm = (wave >> 1) * 64;
    const int wn = (wave & 1) * 64;
    const int m0 = blockIdx.y * BM;
    const int n0 = blockIdx.x * BN;
    const int K = DD2, N = DD;

    for (int i = tid; i < K; i += 256) {
        scs[i] = scale[i];
        shs[i] = shift[i];
    }
    __syncthreads();

    f32x4 acc[4][4] = {};

    for (int kb = 0; kb < K; kb += 128) {
        if (kb) __syncthreads();
#pragma unroll
        for (int c4 = 0; c4 < 4; ++c4) {
            const int k0 = kb + c4 * 32;
#pragma unroll
            for (int s = 0; s < 2; ++s) {
                const int o   = wave * 128 + s * 64 + lane;
                const int row = o >> 2;
                const int cg  = o & 3;
                g2lds16(Wt + (size_t)(n0 + row) * K + k0 + cg * 8,
                        &AsB[1][c4][(size_t)(wave * 128 + s * 64) * 8]);
            }
        }
#pragma unroll
        for (int c4 = 0; c4 < 4; ++c4) {
            const int k0 = kb + c4 * 32;
#pragma unroll
            for (int s = 0; s < 2; ++s) {
                const int o   = wave * 128 + s * 64 + lane;
                const int row = o >> 2;
                const int cg  = o & 3;
                const us8 a8 = *(const us8*)&A[(size_t)(m0 + row) * K + k0 + cg * 8];
                const float4 s4a = *(const float4*)&scs[k0 + cg * 8];
                const float4 s4b = *(const float4*)&scs[k0 + cg * 8 + 4];
                const float4 h4a = *(const float4*)&shs[k0 + cg * 8];
                const float4 h4b = *(const float4*)&shs[k0 + cg * 8 + 4];
                us8 t8;
                t8[0] = f2bf(fmaxf(fmaf(bf2f(a8[0]), s4a.x, h4a.x), 0.0f));
                t8[1] = f2bf(fmaxf(fmaf(bf2f(a8[1]), s4a.y, h4a.y), 0.0f));
                t8[2] = f2bf(fmaxf(fmaf(bf2f(a8[2]), s4a.z, h4a.z), 0.0f));
                t8[3] = f2bf(fmaxf(fmaf(bf2f(a8[3]), s4a.w, h4a.w), 0.0f));
                t8[4] = f2bf(fmaxf(fmaf(bf2f(a8[4]), s4b.x, h4b.x), 0.0f));
                t8[5] = f2bf(fmaxf(fmaf(bf2f(a8[5]), s4b.y, h4b.y), 0.0f));
                t8[6] = f2bf(fmaxf(fmaf(bf2f(a8[6]), s4b.z, h4b.z), 0.0f));
                t8[7] = f2bf(fmaxf(fmaf(bf2f(a8[7]), s4b.w, h4b.w), 0.0f));
                *(us8*)&AsB[0][c4][row * BK + cg * 8] = t8;
            }
        }
        __syncthreads();
#pragma unroll
        for (int c4 = 0; c4 < 4; ++c4) {
            short8 af[4], bfr[4];
#pragma unroll
            for (int i = 0; i < 4; ++i)
                af[i] = *(const short8*)&AsB[0][c4][(wm + i * 16 + r) * BK + qd * 8];
#pragma unroll
            for (int j = 0; j < 4; ++j)
                bfr[j] = *(const short8*)&AsB[1][c4][(wn + j * 16 + r) * BK + qd * 8];
#pragma unroll
            for (int i = 0; i < 4; ++i)
#pragma unroll
                for (int j = 0; j < 4; ++j)
                    acc[i][j] = __builtin_amdgcn_mfma_f32_16x16x32_bf16(af[i], bfr[j], acc[i][j], 0, 0, 0);
        }
    }
    __syncthreads();

    ushortt* Cs = &AsB[0][0][0];
#pragma unroll
    for (int j = 0; j < 4; ++j) {
        const int coll = wn + j * 16 + r;
        const float bv = bias[n0 + coll];
        float s = 0.0f, q = 0.0f;
#pragma unroll
        for (int i = 0; i < 4; ++i)
#pragma unroll
            for (int t = 0; t < 4; ++t) {
                const float v = acc[i][j][t] + bv;
                Cs[(wm + i * 16 + qd * 4 + t) * BN + coll] = f2bf(v);
                s += v;
                q = fmaf(v, v, q);
            }
        s += __shfl_xor(s, 16); s += __shfl_xor(s, 32);
        q += __shfl_xor(q, 16); q += __shfl_xor(q, 32);
        if (qd == 0) {
            redS[wave >> 1][coll] = s;
            redQ[wave >> 1][coll] = q;
        }
    }
    __syncthreads();
    if (tid < BN) {
        psOut[(size_t)blockIdx.y * N + n0 + tid] = redS[0][tid] + redS[1][tid];
        pqOut[(size_t)blockIdx.y * N + n0 + tid] = redQ[0][tid] + redQ[1][tid];
    }
#pragma unroll
    for (int s8 = 0; s8 < 8; ++s8) {
        const int c    = tid + 256 * s8;
        const int row  = c >> 4;
        const int colc = (c & 15) * 8;
        const us8 v = *(const us8*)&Cs[row * BN + colc];
        *(us8*)&C[(size_t)(m0 + row) * N + n0 + colc] = v;
    }
}

// ---------------------------------------------------------------------------
// agg2: in-block adjacency rebuild (packed counts, no Madj) + fused
// finalize(g1) + post staging + s2 = M @ post via MFMA. Grid (2, BGR).
__global__ __launch_bounds__(256) void agg2_mm(const ushortt* __restrict__ h,
                                               const float* __restrict__ psum,
                                               const float* __restrict__ psumsq,
                                               const float* __restrict__ g,
                                               const float* __restrict__ be,
                                               const float* __restrict__ vemb,
                                               const int* __restrict__ ei,
                                               ushortt* __restrict__ s2) {
    __shared__ __align__(16) ushortt Ms[NPG * MP];     // 34816
    __shared__ __align__(16) ushortt PT[NPG * MP];     // 34816 (aliased cnt)
    __shared__ double redS[2][128];
    __shared__ double redQ[2][128];
    __shared__ float scs[128], shs[128];
    int* cnt = (int*)PT;                               // 32768 <= 34816
    const int nb = blockIdx.x, b = blockIdx.y, t = threadIdx.x;
    const int wave = t >> 6, lane = t & 63;
    const int qd = lane >> 4, r = lane & 15;
    const int wm = (wave >> 1) * 64, wn = (wave & 1) * 64;

    // Phase 0: packed adjacency counts
    for (int i = t; i < NPG * NPG / 2; i += 256) cnt[i] = 0;
    __syncthreads();
    for (int e = t; e < EPG; e += 256) {
        const int src = ei[b * EPG + e] - b * NPG;
        const int dst = ei[ETOT + b * EPG + e] - b * NPG;
        const int idx = dst * NPG + src;
        atomicAdd(&cnt[idx >> 1], 1 << ((idx & 1) * 16));
    }
    // Phase 0b: fused finalize partial reduction (independent of cnt)
    {
        const int cl = t & 127, half = t >> 7;
        const int c = nb * 128 + cl;
        double s = 0.0, q = 0.0;
#pragma unroll 4
        for (int k = half * 128; k < half * 128 + 128; ++k) {
            s += (double)psum[(size_t)k * DD + c];
            q += (double)psumsq[(size_t)k * DD + c];
        }
        redS[half][cl] = s;
        redQ[half][cl] = q;
    }
    __syncthreads();
    // Phase 1: cnt -> Ms; scs/shs from reduced partials
#pragma unroll
    for (int k = 0; k < 8; ++k) {
        const int ch = t + k * 256;
        const int m = ch >> 4, sc = (ch & 15) * 8;
        us8 o;
#pragma unroll
        for (int e = 0; e < 8; ++e) {
            const int i = m * NPG + sc + e;
            const int v = ((cnt[i >> 1] >> ((i & 1) * 16)) & 0xffff) + (m == sc + e ? 1 : 0);
            o[e] = f2bf((float)v);
        }
        *(us8*)&Ms[m * MP + sc] = o;
    }
    if (t < 128) {
        const int c = nb * 128 + t;
        const double s = redS[0][t] + redS[1][t];
        const double q = redQ[0][t] + redQ[1][t];
        const double mean = s / (double)NTOT;
        const double var = q / (double)NTOT - mean * mean;
        const double rs = 1.0 / sqrt(var + 1e-5);
        const float sc = (float)((double)g[c] * rs);
        scs[t] = sc;
        shs[t] = (float)((double)be[c] - mean * (double)sc);
    }
    __syncthreads();   // cnt dead, scs ready
    // Phase 2: post staging (overwrites cnt region)
#pragma unroll
    for (int k = 0; k < 8; ++k) {
        const int ch = t + k * 256;
        const int cl = ch & 127, s8 = ch >> 7;
        const float scv = scs[cl], shv = shs[cl], vev = vemb[nb * 128 + cl];
        us8 o;
#pragma unroll
        for (int j = 0; j < 8; ++j) {
            float v = fmaf(bf2f(h[(size_t)(b * NPG + s8 * 8 + j) * DD + nb * 128 + cl]), scv, shv);
            o[j] = f2bf(fmaxf(v, 0.0f) + vev);
        }
        *(us8*)&PT[cl * MP + s8 * 8] = o;
    }
    __syncthreads();
    // Phase 3: s2 = Ms @ PT^T
    f32x4 acc[4][4] = {};
#pragma unroll
    for (int ks = 0; ks < 4; ++ks) {
        const int k0 = ks * 32 + qd * 8;
        short8 af[4], bfr[4];
#pragma unroll
        for (int i = 0; i < 4; ++i)
            af[i] = *(const short8*)&Ms[(wm + i * 16 + r) * MP + k0];
#pragma unroll
        for (int j = 0; j < 4; ++j)
            bfr[j] = *(const short8*)&PT[(wn + j * 16 + r) * MP + k0];
#pragma unroll
        for (int i = 0; i < 4; ++i)
#pragma unroll
            for (int j = 0; j < 4; ++j)
                acc[i][j] = __builtin_amdgcn_mfma_f32_16x16x32_bf16(af[i], bfr[j], acc[i][j], 0, 0, 0);
    }
    __syncthreads();
    ushortt* Cs = Ms;
#pragma unroll
    for (int j = 0; j < 4; ++j) {
        const int coll = wn + j * 16 + r;
#pragma unroll
        for (int i = 0; i < 4; ++i)
#pragma unroll
            for (int tt = 0; tt < 4; ++tt)
                Cs[(wm + i * 16 + qd * 4 + tt) * 128 + coll] = f2bf(acc[i][j][tt]);
    }
    __syncthreads();
#pragma unroll
    for (int k = 0; k < 8; ++k) {
        const int ch = t + k * 256;
        const int row = ch >> 4, colc = (ch & 15) * 8;
        *(us8*)&s2[(size_t)(b * NPG + row) * DD + nb * 128 + colc] =
            *(const us8*)&Cs[row * 128 + colc];
    }
}

// ---------------------------------------------------------------------------
// Mega tail (unchanged).
__global__ __launch_bounds__(EPG) void sort_mega(const ushortt* __restrict__ h2,
                                                 const float* __restrict__ psum,
                                                 const float* __restrict__ psumsq,
                                                 const float* __restrict__ g,
                                                 const float* __restrict__ be,
                                                 const float* __restrict__ Wl,
                                                 const float* __restrict__ bl,
                                                 const int* __restrict__ ei,
                                                 float* __restrict__ out) {
    __shared__ double redS[2][DD];
    __shared__ double redQ[2][DD];
    __shared__ float scs[DD], shs[DD];
    __shared__ float pa[NPG], pb[NPG];
    __shared__ float pw[EPG];
    __shared__ int ord[EPG];
    const int b = blockIdx.x, t = threadIdx.x;
    {
        const int c = t & 255, half = t >> 8;
        double s = 0.0, q = 0.0;
#pragma unroll 4
        for (int k = half * 128; k < half * 128 + 128; ++k) {
            s += (double)psum[(size_t)k * DD + c];
            q += (double)psumsq[(size_t)k * DD + c];
        }
        redS[half][c] = s;
        redQ[half][c] = q;
    }
    __syncthreads();
    if (t < DD) {
        const double s = redS[0][t] + redS[1][t];
        const double q = redQ[0][t] + redQ[1][t];
        const double mean = s / (double)NTOT;
        const double var = q / (double)NTOT - mean * mean;
        const double rs = 1.0 / sqrt(var + 1e-5);
        const float sc = (float)((double)g[t] * rs);
        scs[t] = sc;
        shs[t] = (float)((double)be[t] - mean * (double)sc);
    }
    __syncthreads();
    {
        const int wave = t >> 6, lane = t & 63;
        const float4 w0 = *(const float4*)&Wl[lane * 4];
        const float4 w1 = *(const float4*)&Wl[DD + lane * 4];
        const float4 sc4 = *(const float4*)&scs[lane * 4];
        const float4 sh4 = *(const float4*)&shs[lane * 4];
        for (int n = wave; n < NPG; n += 8) {
            const us4 z4 = *(const us4*)&h2[(size_t)(b * NPG + n) * DD + lane * 4];
            const float x0 = fmaf(bf2f(z4.x), sc4.x, sh4.x);
            const float x1 = fmaf(bf2f(z4.y), sc4.y, sh4.y);
            const float x2 = fmaf(bf2f(z4.z), sc4.z, sh4.z);
            const float x3 = fmaf(bf2f(z4.w), sc4.w, sh4.w);
            float sa = x0 * w0.x + x1 * w0.y + x2 * w0.z + x3 * w0.w;
            float sb = x0 * w1.x + x1 * w1.y + x2 * w1.z + x3 * w1.w;
#pragma unroll
            for (int off = 32; off >= 1; off >>= 1) {
                sa += __shfl_down(sa, off);
                sb += __shfl_down(sb, off);
            }
            if (lane == 0) { pa[n] = sa; pb[n] = sb; }
        }
    }
    __syncthreads();
    const int rl = ei[b * EPG + t] - b * NPG;
    const int cl = ei[ETOT + b * EPG + t] - b * NPG;
    const float v = pa[rl] + pb[cl] + bl[0];
    pw[t] = v;
    out[OFF_PRED + b * EPG + t] = v;
    __syncthreads();
    int rank = 0;
#pragma unroll 8
    for (int k = 0; k < EPG; ++k) {
        const float u = pw[k];
        rank += (u > v) || (u == v && k < t);
    }
    ord[rank] = t;
    __syncthreads();
    const int j = ord[t];
    const float wv = pw[j];
    const float e0 = (float)ei[b * EPG + j];
    const float e1 = (float)ei[ETOT + b * EPG + j];
    if (t < NRES) {
        out[OFF_CEI + b * NRES + t] = e0;
        out[OFF_CEI + BGR * NRES + b * NRES + t] = e1;
        out[OFF_CW + b * NRES + t] = wv;
    } else {
        const int p = t - NRES;
        out[OFF_FEI + b * NRES + p] = e0;
        out[OFF_FEI + BGR * NRES + b * NRES + p] = e1;
        out[OFF_FW + b * NRES + p] = -wv;
    }
}

// ---------------------------------------------------------------------------
extern "C" void kernel_launch(void* const* d_in, const int* in_sizes, int n_in,
                              void* d_out, int out_size, void* d_ws, size_t ws_size,
                              hipStream_t stream) {
    (void)in_sizes; (void)n_in; (void)out_size; (void)ws_size;
    const float* x    = (const float*)d_in[0];
    const int*   ei   = (const int*)d_in[1];
    const float* vemb = (const float*)d_in[3];
    const float* W1a  = (const float*)d_in[4];
    const float* b1a  = (const float*)d_in[5];
    const float* g1a  = (const float*)d_in[6];
    const float* be1a = (const float*)d_in[7];
    const float* W1b  = (const float*)d_in[8];
    const float* b1b  = (const float*)d_in[9];
    const float* g1   = (const float*)d_in[10];
    const float* be1  = (const float*)d_in[11];
    const float* W2a  = (const float*)d_in[12];
    const float* b2a  = (const float*)d_in[13];
    const float* g2a  = (const float*)d_in[14];
    const float* be2a = (const float*)d_in[15];
    const float* W2b  = (const float*)d_in[16];
    const float* b2b  = (const float*)d_in[17];
    const float* g2   = (const float*)d_in[18];
    const float* be2  = (const float*)d_in[19];
    const float* Wl   = (const float*)d_in[20];
    const float* bl   = (const float*)d_in[21];
    float* out = (float*)d_out;

    char* wp = (char*)d_ws;
    auto alloc = [&](size_t bytes) -> char* {
        char* r = wp;
        wp += (bytes + 255) & ~(size_t)255;
        return r;
    };
    ushortt* zb    = (ushortt*)alloc((size_t)NTOT * 512 * 2);  // z1 / z2
    ushortt* bufC  = (ushortt*)alloc((size_t)NTOT * 256 * 2);  // h1 / h2
    ushortt* bufS1 = (ushortt*)alloc((size_t)NTOT * 128 * 2);  // s1
    ushortt* bufS2 = (ushortt*)alloc((size_t)NTOT * 256 * 2);  // s2
    ushortt* Wt1a  = (ushortt*)alloc((size_t)DIN * DD2 * 2);
    ushortt* Wt1b  = (ushortt*)alloc((size_t)DD2 * DD * 2);
    ushortt* Wt2a  = (ushortt*)alloc((size_t)DD * DD2 * 2);
    ushortt* Wt2b  = (ushortt*)alloc((size_t)DD2 * DD * 2);
    float*   psA   = (float*)alloc((size_t)256 * DD2 * 4);
    float*   pqA   = (float*)alloc((size_t)256 * DD2 * 4);
    float*   psB   = (float*)alloc((size_t)256 * DD * 4);
    float*   pqB   = (float*)alloc((size_t)256 * DD * 4);
    float*   scA   = (float*)alloc(DD2 * 4);
    float*   shA   = (float*)alloc(DD2 * 4);

    // 1) weights + (adjacency, s1) in one dispatch
    prep<<<2048, 256, 0, stream>>>(W1a, W1b, W2a, W2b, x, ei,
                                   Wt1a, Wt1b, Wt2a, Wt2b, bufS1);

    // 2) z1 = s1 @ W1a + b1a (+stats)
    gemm_mfma<<<dim3(DD2 / BN, NTOT / BM), 256, 0, stream>>>(bufS1, Wt1a, b1a, zb, psA, pqA, NTOT, DD2, DIN);
    bn_finalize<<<2, 256, 0, stream>>>(psA, pqA, g1a, be1a, DD2, scA, shA);

    // 3) h1 = relu(BN(z1)) @ W1b + b1b (+stats)
    gemm_bn<<<dim3(DD / BN, NTOT / BM), 256, 0, stream>>>(zb, Wt1b, scA, shA, b1b, bufC, psB, pqB);

    // 4) s2 = M @ (relu(BN(h1)) + vemb)  [adjacency rebuilt in-block]
    agg2_mm<<<dim3(2, BGR), 256, 0, stream>>>(bufC, psB, pqB, g1, be1, vemb, ei, bufS2);

    // 5) z2 = s2 @ W2a + b2a (+stats)
    gemm_mfma<<<dim3(DD2 / BN, NTOT / BM), 256, 0, stream>>>(bufS2, Wt2a, b2a, zb, psA, pqA, NTOT, DD2, DD);
    bn_finalize<<<2, 256, 0, stream>>>(psA, pqA, g2a, be2a, DD2, scA, shA);

    // 6) h2 = relu(BN(z2)) @ W2b + b2b (+stats)
    gemm_bn<<<dim3(DD / BN, NTOT / BM), 256, 0, stream>>>(zb, Wt2b, scA, shA, b2b, bufC, psB, pqB);

    // 7) mega tail (finalize(g2) fused)
    sort_mega<<<BGR, EPG, 0, stream>>>(bufC, psB, pqB, g2, be2, Wl, bl, ei, out);
}

// Round 17
// 293.219 us; speedup vs baseline: 1.8373x; 1.0253x over previous
//
#include <hip/hip_runtime.h>

// Problem constants
#define BGR   256
#define NPG   128
#define EPG   512
#define DIN   128
#define DD    256
#define DD2   512
#define NTOT  (BGR * NPG)   // 32768
#define ETOT  (BGR * EPG)   // 131072
#define NRES  (EPG / 2)
#define NCHUNK 256
#define MP    136           // padded LDS stride (ushorts)

// Output layout (floats)
#define OFF_CEI  0
#define OFF_CW   (2 * BGR * NRES)
#define OFF_FEI  (OFF_CW + BGR * NRES)
#define OFF_FW   (OFF_FEI + 2 * BGR * NRES)
#define OFF_PRED (OFF_FW + BGR * NRES)

typedef unsigned short ushortt;
typedef __attribute__((ext_vector_type(4))) unsigned short us4;
typedef __attribute__((ext_vector_type(8))) unsigned short us8;
typedef __attribute__((ext_vector_type(8))) short short8;
typedef __attribute__((ext_vector_type(4))) float f32x4;

__device__ __forceinline__ ushortt f2bf(float f) {
    unsigned int u = __float_as_uint(f);
    unsigned int r = (u + 0x7fffu + ((u >> 16) & 1u)) >> 16;
    return (ushortt)r;
}
__device__ __forceinline__ float bf2f(ushortt u) {
    return __uint_as_float(((unsigned int)u) << 16);
}

__device__ __forceinline__ void g2lds16(const void* g, void* l) {
    __builtin_amdgcn_global_load_lds(
        (const __attribute__((address_space(1))) unsigned int*)g,
        (__attribute__((address_space(3))) unsigned int*)l, 16, 0, 0);
}

// ---------------------------------------------------------------------------
// prep: blocks 0..111 = tiled weight transposes (coalesced both directions);
// blocks 112..367 = per-graph adjacency (packed u16 counts) +
// s1 = bf16(M @ bf16(x)) via MFMA entirely in LDS. 68 KB -> 2 blocks/CU,
// 368 blocks -> single occupancy round.
__global__ __launch_bounds__(256) void prep(const float* __restrict__ W1a,
                                            const float* __restrict__ W1b,
                                            const float* __restrict__ W2a,
                                            const float* __restrict__ W2b,
                                            const float* __restrict__ x,
                                            const int* __restrict__ ei,
                                            ushortt* __restrict__ Wt1a,
                                            ushortt* __restrict__ Wt1b,
                                            ushortt* __restrict__ Wt2a,
                                            ushortt* __restrict__ Wt2b,
                                            ushortt* __restrict__ s1) {
    __shared__ __align__(16) char smem[69632];
    const int t = threadIdx.x;
    const int blk = blockIdx.x;
    if (blk < 112) {
        // 64x64 tile transpose: coalesced f32x4 loads, LDS (stride 67), us8 stores
        const float* W; ushortt* Wt; int Nsrc, Ktot, kr0, nc0;
        if (blk < 16)       { W = W1a; Wt = Wt1a; Nsrc = 512; Ktot = 128;
                              kr0 = (blk >> 3) * 64;        nc0 = (blk & 7) * 64; }
        else if (blk < 48)  { const int i = blk - 16; W = W1b; Wt = Wt1b; Nsrc = 256; Ktot = 512;
                              kr0 = (i >> 2) * 64;          nc0 = (i & 3) * 64; }
        else if (blk < 80)  { const int i = blk - 48; W = W2a; Wt = Wt2a; Nsrc = 512; Ktot = 256;
                              kr0 = (i >> 3) * 64;          nc0 = (i & 7) * 64; }
        else                { const int i = blk - 80; W = W2b; Wt = Wt2b; Nsrc = 256; Ktot = 512;
                              kr0 = (i >> 2) * 64;          nc0 = (i & 3) * 64; }
        ushortt* tile = (ushortt*)smem;   // [64][67]
#pragma unroll
        for (int kk = 0; kk < 4; ++kk) {
            const int idx = t + kk * 256;          // 0..1023
            const int rr = idx >> 4, c4 = (idx & 15) * 4;
            const float4 v = *(const float4*)&W[(size_t)(kr0 + rr) * Nsrc + nc0 + c4];
            tile[rr * 67 + c4 + 0] = f2bf(v.x);
            tile[rr * 67 + c4 + 1] = f2bf(v.y);
            tile[rr * 67 + c4 + 2] = f2bf(v.z);
            tile[rr * 67 + c4 + 3] = f2bf(v.w);
        }
        __syncthreads();
#pragma unroll
        for (int kk = 0; kk < 2; ++kk) {
            const int idx = t + kk * 256;          // 0..511
            const int n = idx >> 3, k8 = (idx & 7) * 8;
            us8 o;
#pragma unroll
            for (int j = 0; j < 8; ++j) o[j] = tile[(k8 + j) * 67 + n];
            *(us8*)&Wt[(size_t)(nc0 + n) * Ktot + kr0 + k8] = o;
        }
        return;
    }
    const int b = blk - 112;
    ushortt* Ms = (ushortt*)smem;                    // [128][136] = 34816
    int* cnt = (int*)(smem + 34816);                 // 32768 (2x u16 packed)
    ushortt* XT = (ushortt*)(smem + 34816);          // [128][136] alias
    ushortt* Cs = (ushortt*)(smem + 34816);          // [128][128] alias
    const int wave = t >> 6, lane = t & 63;
    const int qd = lane >> 4, r = lane & 15;
    const int wm = (wave >> 1) * 64, wn = (wave & 1) * 64;

    // Phase 0: packed adjacency counts (commutative exact -> deterministic)
    for (int i = t; i < NPG * NPG / 2; i += 256) cnt[i] = 0;
    __syncthreads();
    for (int e = t; e < EPG; e += 256) {
        const int src = ei[b * EPG + e] - b * NPG;
        const int dst = ei[ETOT + b * EPG + e] - b * NPG;
        const int idx = dst * NPG + src;
        atomicAdd(&cnt[idx >> 1], 1 << ((idx & 1) * 16));
    }
    __syncthreads();
    // Phase 1: cnt -> Ms (bf16, + identity)
#pragma unroll
    for (int k = 0; k < 8; ++k) {
        const int ch = t + k * 256;
        const int m = ch >> 4, sc = (ch & 15) * 8;
        us8 o;
#pragma unroll
        for (int e = 0; e < 8; ++e) {
            const int i = m * NPG + sc + e;
            const int v = ((cnt[i >> 1] >> ((i & 1) * 16)) & 0xffff) + (m == sc + e ? 1 : 0);
            o[e] = f2bf((float)v);
        }
        *(us8*)&Ms[m * MP + sc] = o;
    }
    __syncthreads();   // cnt dead

    // Phase 2: x -> XT (chunked transpose)
#pragma unroll
    for (int k = 0; k < 8; ++k) {
        const int ch = t + k * 256;
        const int c = ch & 127, s8 = ch >> 7;
        us8 o;
#pragma unroll
        for (int j = 0; j < 8; ++j)
            o[j] = f2bf(x[(size_t)(b * NPG + s8 * 8 + j) * DIN + c]);
        *(us8*)&XT[c * MP + s8 * 8] = o;
    }
    __syncthreads();

    // Phase 3: s1 = Ms @ XT^T
    f32x4 acc[4][4] = {};
#pragma unroll
    for (int ks = 0; ks < 4; ++ks) {
        const int k0 = ks * 32 + qd * 8;
        short8 af[4], bfr[4];
#pragma unroll
        for (int i = 0; i < 4; ++i)
            af[i] = *(const short8*)&Ms[(wm + i * 16 + r) * MP + k0];
#pragma unroll
        for (int j = 0; j < 4; ++j)
            bfr[j] = *(const short8*)&XT[(wn + j * 16 + r) * MP + k0];
#pragma unroll
        for (int i = 0; i < 4; ++i)
#pragma unroll
            for (int j = 0; j < 4; ++j)
                acc[i][j] = __builtin_amdgcn_mfma_f32_16x16x32_bf16(af[i], bfr[j], acc[i][j], 0, 0, 0);
    }
    __syncthreads();   // XT dead
#pragma unroll
    for (int j = 0; j < 4; ++j) {
        const int coll = wn + j * 16 + r;
#pragma unroll
        for (int i = 0; i < 4; ++i)
#pragma unroll
            for (int tt = 0; tt < 4; ++tt)
                Cs[(wm + i * 16 + qd * 4 + tt) * 128 + coll] = f2bf(acc[i][j][tt]);
    }
    __syncthreads();
#pragma unroll
    for (int k = 0; k < 8; ++k) {
        const int ch = t + k * 256;
        const int row = ch >> 4, colc = (ch & 15) * 8;
        *(us8*)&s1[(size_t)(b * NPG + row) * DIN + colc] = *(const us8*)&Cs[row * 128 + colc];
    }
}

// ---------------------------------------------------------------------------
// z-GEMM: C = A@Wt^T + bias (bf16 out), fused fp32 BN partials, batched
// 4-chunk async staging (R14 verified).
#define BM 128
#define BN 128
#define BK 32
__global__ __launch_bounds__(256) void gemm_mfma(const ushortt* __restrict__ A,
                                                 const ushortt* __restrict__ Wt,
                                                 const float* __restrict__ bias,
                                                 ushortt* __restrict__ C,
                                                 float* __restrict__ psum,
                                                 float* __restrict__ psumsq,
                                                 int M, int N, int K) {
    __shared__ __align__(16) ushortt AsB[2][4][BM * BK];   // 64 KB
    __shared__ float redS[2][BN];
    __shared__ float redQ[2][BN];
    const int tid  = threadIdx.x;
    const int wave = tid >> 6;
    const int lane = tid & 63;
    const int qd = lane >> 4;
    const int r  = lane & 15;
    const int wm = (wave >> 1) * 64;
    const int wn = (wave & 1) * 64;
    const int m0 = blockIdx.y * BM;
    const int n0 = blockIdx.x * BN;

    f32x4 acc[4][4] = {};

    for (int kb = 0; kb < K; kb += 128) {
        if (kb) __syncthreads();
#pragma unroll
        for (int c4 = 0; c4 < 4; ++c4) {
            const int k0 = kb + c4 * 32;
#pragma unroll
            for (int s = 0; s < 2; ++s) {
                const int o   = wave * 128 + s * 64 + lane;
                const int row = o >> 2;
                const int cg  = o & 3;
                g2lds16(A  + (size_t)(m0 + row) * K + k0 + cg * 8,
                        &AsB[0][c4][(size_t)(wave * 128 + s * 64) * 8]);
                g2lds16(Wt + (size_t)(n0 + row) * K + k0 + cg * 8,
                        &AsB[1][c4][(size_t)(wave * 128 + s * 64) * 8]);
            }
        }
        __syncthreads();
#pragma unroll
        for (int c4 = 0; c4 < 4; ++c4) {
            short8 af[4], bfr[4];
#pragma unroll
            for (int i = 0; i < 4; ++i)
                af[i] = *(const short8*)&AsB[0][c4][(wm + i * 16 + r) * BK + qd * 8];
#pragma unroll
            for (int j = 0; j < 4; ++j)
                bfr[j] = *(const short8*)&AsB[1][c4][(wn + j * 16 + r) * BK + qd * 8];
#pragma unroll
            for (int i = 0; i < 4; ++i)
#pragma unroll
                for (int j = 0; j < 4; ++j)
                    acc[i][j] = __builtin_amdgcn_mfma_f32_16x16x32_bf16(af[i], bfr[j], acc[i][j], 0, 0, 0);
        }
    }
    __syncthreads();

    ushortt* Cs = &AsB[0][0][0];
#pragma unroll
    for (int j = 0; j < 4; ++j) {
        const int coll = wn + j * 16 + r;
        const float bv = bias[n0 + coll];
        float s = 0.0f, q = 0.0f;
#pragma unroll
        for (int i = 0; i < 4; ++i)
#pragma unroll
            for (int t = 0; t < 4; ++t) {
                const float v = acc[i][j][t] + bv;
                Cs[(wm + i * 16 + qd * 4 + t) * BN + coll] = f2bf(v);
                s += v;
                q = fmaf(v, v, q);
            }
        s += __shfl_xor(s, 16); s += __shfl_xor(s, 32);
        q += __shfl_xor(q, 16); q += __shfl_xor(q, 32);
        if (qd == 0) {
            redS[wave >> 1][coll] = s;
            redQ[wave >> 1][coll] = q;
        }
    }
    __syncthreads();
    if (tid < BN) {
        psum[(size_t)blockIdx.y * N + n0 + tid]   = redS[0][tid] + redS[1][tid];
        psumsq[(size_t)blockIdx.y * N + n0 + tid] = redQ[0][tid] + redQ[1][tid];
    }
#pragma unroll
    for (int s8 = 0; s8 < 8; ++s8) {
        const int c    = tid + 256 * s8;
        const int row  = c >> 4;
        const int colc = (c & 15) * 8;
        const us8 v = *(const us8*)&Cs[row * BN + colc];
        *(us8*)&C[(size_t)(m0 + row) * N + n0 + colc] = v;
    }
}

// ---------------------------------------------------------------------------
__global__ __launch_bounds__(256) void bn_finalize(const float* __restrict__ psum,
                                                   const float* __restrict__ psumsq,
                                                   const float* __restrict__ g,
                                                   const float* __restrict__ be,
                                                   int ncols,
                                                   float* __restrict__ scale,
                                                   float* __restrict__ shift) {
    const int c = blockIdx.x * 256 + threadIdx.x;
    double s = 0.0, s2 = 0.0;
    for (int k = 0; k < NCHUNK; ++k) {
        s += (double)psum[(size_t)k * ncols + c];
        s2 += (double)psumsq[(size_t)k * ncols + c];
    }
    const double mean = s / (double)NTOT;
    const double var = s2 / (double)NTOT - mean * mean;
    const double rs = 1.0 / sqrt(var + 1e-5);
    const float sc = (float)((double)g[c] * rs);
    scale[c] = sc;
    shift[c] = (float)((double)be[c] - mean * (double)sc);
}

// ---------------------------------------------------------------------------
// h-GEMM: C = relu(BN(A))@Wt^T + bias, batched staging (R14 verified).
__global__ __launch_bounds__(256) void gemm_bn(const ushortt* __restrict__ A,
                                               const ushortt* __restrict__ Wt,
                                               const float* __restrict__ scale,
                                               const float* __restrict__ shift,
                                               const float* __restrict__ bias,
                                               ushortt* __restrict__ C,
                                               float* __restrict__ psOut,
                                               float* __restrict__ pqOut) {
    __shared__ __align__(16) ushortt AsB[2][4][BM * BK];   // 64 KB
    __shared__ float redS[2][BN];
    __shared__ float redQ[2][BN];
    __shared__ float scs[DD2], shs[DD2];
    const int tid  = threadIdx.x;
    const int wave = tid >> 6;
    const int lane = tid & 63;
    const int qd = lane >> 4;
    const int r  = lane & 15;
    const int wm = (wave >> 1) * 64;
    const int wn = (wave & 1) * 64;
    const int m0 = blockIdx.y * BM;
    const int n0 = blockIdx.x * BN;
    const int K = DD2, N = DD;

    for (int i = tid; i < K; i += 256) {
        scs[i] = scale[i];
        shs[i] = shift[i];
    }
    __syncthreads();

    f32x4 acc[4][4] = {};

    for (int kb = 0; kb < K; kb += 128) {
        if (kb) __syncthreads();
#pragma unroll
        for (int c4 = 0; c4 < 4; ++c4) {
            const int k0 = kb + c4 * 32;
#pragma unroll
            for (int s = 0; s < 2; ++s) {
                const int o   = wave * 128 + s * 64 + lane;
                const int row = o >> 2;
                const int cg  = o & 3;
                g2lds16(Wt + (size_t)(n0 + row) * K + k0 + cg * 8,
                        &AsB[1][c4][(size_t)(wave * 128 + s * 64) * 8]);
            }
        }
#pragma unroll
        for (int c4 = 0; c4 < 4; ++c4) {
            const int k0 = kb + c4 * 32;
#pragma unroll
            for (int s = 0; s < 2; ++s) {
                const int o   = wave * 128 + s * 64 + lane;
                const int row = o >> 2;
                const int cg  = o & 3;
                const us8 a8 = *(const us8*)&A[(size_t)(m0 + row) * K + k0 + cg * 8];
                const float4 s4a = *(const float4*)&scs[k0 + cg * 8];
                const float4 s4b = *(const float4*)&scs[k0 + cg * 8 + 4];
                const float4 h4a = *(const float4*)&shs[k0 + cg * 8];
                const float4 h4b = *(const float4*)&shs[k0 + cg * 8 + 4];
                us8 t8;
                t8[0] = f2bf(fmaxf(fmaf(bf2f(a8[0]), s4a.x, h4a.x), 0.0f));
                t8[1] = f2bf(fmaxf(fmaf(bf2f(a8[1]), s4a.y, h4a.y), 0.0f));
                t8[2] = f2bf(fmaxf(fmaf(bf2f(a8[2]), s4a.z, h4a.z), 0.0f));
                t8[3] = f2bf(fmaxf(fmaf(bf2f(a8[3]), s4a.w, h4a.w), 0.0f));
                t8[4] = f2bf(fmaxf(fmaf(bf2f(a8[4]), s4b.x, h4b.x), 0.0f));
                t8[5] = f2bf(fmaxf(fmaf(bf2f(a8[5]), s4b.y, h4b.y), 0.0f));
                t8[6] = f2bf(fmaxf(fmaf(bf2f(a8[6]), s4b.z, h4b.z), 0.0f));
                t8[7] = f2bf(fmaxf(fmaf(bf2f(a8[7]), s4b.w, h4b.w), 0.0f));
                *(us8*)&AsB[0][c4][row * BK + cg * 8] = t8;
            }
        }
        __syncthreads();
#pragma unroll
        for (int c4 = 0; c4 < 4; ++c4) {
            short8 af[4], bfr[4];
#pragma unroll
            for (int i = 0; i < 4; ++i)
                af[i] = *(const short8*)&AsB[0][c4][(wm + i * 16 + r) * BK + qd * 8];
#pragma unroll
            for (int j = 0; j < 4; ++j)
                bfr[j] = *(const short8*)&AsB[1][c4][(wn + j * 16 + r) * BK + qd * 8];
#pragma unroll
            for (int i = 0; i < 4; ++i)
#pragma unroll
                for (int j = 0; j < 4; ++j)
                    acc[i][j] = __builtin_amdgcn_mfma_f32_16x16x32_bf16(af[i], bfr[j], acc[i][j], 0, 0, 0);
        }
    }
    __syncthreads();

    ushortt* Cs = &AsB[0][0][0];
#pragma unroll
    for (int j = 0; j < 4; ++j) {
        const int coll = wn + j * 16 + r;
        const float bv = bias[n0 + coll];
        float s = 0.0f, q = 0.0f;
#pragma unroll
        for (int i = 0; i < 4; ++i)
#pragma unroll
            for (int t = 0; t < 4; ++t) {
                const float v = acc[i][j][t] + bv;
                Cs[(wm + i * 16 + qd * 4 + t) * BN + coll] = f2bf(v);
                s += v;
                q = fmaf(v, v, q);
            }
        s += __shfl_xor(s, 16); s += __shfl_xor(s, 32);
        q += __shfl_xor(q, 16); q += __shfl_xor(q, 32);
        if (qd == 0) {
            redS[wave >> 1][coll] = s;
            redQ[wave >> 1][coll] = q;
        }
    }
    __syncthreads();
    if (tid < BN) {
        psOut[(size_t)blockIdx.y * N + n0 + tid] = redS[0][tid] + redS[1][tid];
        pqOut[(size_t)blockIdx.y * N + n0 + tid] = redQ[0][tid] + redQ[1][tid];
    }
#pragma unroll
    for (int s8 = 0; s8 < 8; ++s8) {
        const int c    = tid + 256 * s8;
        const int row  = c >> 4;
        const int colc = (c & 15) * 8;
        const us8 v = *(const us8*)&Cs[row * BN + colc];
        *(us8*)&C[(size_t)(m0 + row) * N + n0 + colc] = v;
    }
}

// ---------------------------------------------------------------------------
// agg2: in-block adjacency rebuild (packed counts) + fused finalize(g1) +
// post staging + s2 = M @ post via MFMA. Grid (2, BGR).  (R15 verified)
__global__ __launch_bounds__(256) void agg2_mm(const ushortt* __restrict__ h,
                                               const float* __restrict__ psum,
                                               const float* __restrict__ psumsq,
                                               const float* __restrict__ g,
                                               const float* __restrict__ be,
                                               const float* __restrict__ vemb,
                                               const int* __restrict__ ei,
                                               ushortt* __restrict__ s2) {
    __shared__ __align__(16) ushortt Ms[NPG * MP];
    __shared__ __align__(16) ushortt PT[NPG * MP];
    __shared__ double redS[2][128];
    __shared__ double redQ[2][128];
    __shared__ float scs[128], shs[128];
    int* cnt = (int*)PT;
    const int nb = blockIdx.x, b = blockIdx.y, t = threadIdx.x;
    const int wave = t >> 6, lane = t & 63;
    const int qd = lane >> 4, r = lane & 15;
    const int wm = (wave >> 1) * 64, wn = (wave & 1) * 64;

    for (int i = t; i < NPG * NPG / 2; i += 256) cnt[i] = 0;
    __syncthreads();
    for (int e = t; e < EPG; e += 256) {
        const int src = ei[b * EPG + e] - b * NPG;
        const int dst = ei[ETOT + b * EPG + e] - b * NPG;
        const int idx = dst * NPG + src;
        atomicAdd(&cnt[idx >> 1], 1 << ((idx & 1) * 16));
    }
    {
        const int cl = t & 127, half = t >> 7;
        const int c = nb * 128 + cl;
        double s = 0.0, q = 0.0;
#pragma unroll 4
        for (int k = half * 128; k < half * 128 + 128; ++k) {
            s += (double)psum[(size_t)k * DD + c];
            q += (double)psumsq[(size_t)k * DD + c];
        }
        redS[half][cl] = s;
        redQ[half][cl] = q;
    }
    __syncthreads();
#pragma unroll
    for (int k = 0; k < 8; ++k) {
        const int ch = t + k * 256;
        const int m = ch >> 4, sc = (ch & 15) * 8;
        us8 o;
#pragma unroll
        for (int e = 0; e < 8; ++e) {
            const int i = m * NPG + sc + e;
            const int v = ((cnt[i >> 1] >> ((i & 1) * 16)) & 0xffff) + (m == sc + e ? 1 : 0);
            o[e] = f2bf((float)v);
        }
        *(us8*)&Ms[m * MP + sc] = o;
    }
    if (t < 128) {
        const int c = nb * 128 + t;
        const double s = redS[0][t] + redS[1][t];
        const double q = redQ[0][t] + redQ[1][t];
        const double mean = s / (double)NTOT;
        const double var = q / (double)NTOT - mean * mean;
        const double rs = 1.0 / sqrt(var + 1e-5);
        const float sc = (float)((double)g[c] * rs);
        scs[t] = sc;
        shs[t] = (float)((double)be[c] - mean * (double)sc);
    }
    __syncthreads();
#pragma unroll
    for (int k = 0; k < 8; ++k) {
        const int ch = t + k * 256;
        const int cl = ch & 127, s8 = ch >> 7;
        const float scv = scs[cl], shv = shs[cl], vev = vemb[nb * 128 + cl];
        us8 o;
#pragma unroll
        for (int j = 0; j < 8; ++j) {
            float v = fmaf(bf2f(h[(size_t)(b * NPG + s8 * 8 + j) * DD + nb * 128 + cl]), scv, shv);
            o[j] = f2bf(fmaxf(v, 0.0f) + vev);
        }
        *(us8*)&PT[cl * MP + s8 * 8] = o;
    }
    __syncthreads();
    f32x4 acc[4][4] = {};
#pragma unroll
    for (int ks = 0; ks < 4; ++ks) {
        const int k0 = ks * 32 + qd * 8;
        short8 af[4], bfr[4];
#pragma unroll
        for (int i = 0; i < 4; ++i)
            af[i] = *(const short8*)&Ms[(wm + i * 16 + r) * MP + k0];
#pragma unroll
        for (int j = 0; j < 4; ++j)
            bfr[j] = *(const short8*)&PT[(wn + j * 16 + r) * MP + k0];
#pragma unroll
        for (int i = 0; i < 4; ++i)
#pragma unroll
            for (int j = 0; j < 4; ++j)
                acc[i][j] = __builtin_amdgcn_mfma_f32_16x16x32_bf16(af[i], bfr[j], acc[i][j], 0, 0, 0);
    }
    __syncthreads();
    ushortt* Cs = Ms;
#pragma unroll
    for (int j = 0; j < 4; ++j) {
        const int coll = wn + j * 16 + r;
#pragma unroll
        for (int i = 0; i < 4; ++i)
#pragma unroll
            for (int tt = 0; tt < 4; ++tt)
                Cs[(wm + i * 16 + qd * 4 + tt) * 128 + coll] = f2bf(acc[i][j][tt]);
    }
    __syncthreads();
#pragma unroll
    for (int k = 0; k < 8; ++k) {
        const int ch = t + k * 256;
        const int row = ch >> 4, colc = (ch & 15) * 8;
        *(us8*)&s2[(size_t)(b * NPG + row) * DD + nb * 128 + colc] =
            *(const us8*)&Cs[row * 128 + colc];
    }
}

// ---------------------------------------------------------------------------
// Mega tail (unchanged).
__global__ __launch_bounds__(EPG) void sort_mega(const ushortt* __restrict__ h2,
                                                 const float* __restrict__ psum,
                                                 const float* __restrict__ psumsq,
                                                 const float* __restrict__ g,
                                                 const float* __restrict__ be,
                                                 const float* __restrict__ Wl,
                                                 const float* __restrict__ bl,
                                                 const int* __restrict__ ei,
                                                 float* __restrict__ out) {
    __shared__ double redS[2][DD];
    __shared__ double redQ[2][DD];
    __shared__ float scs[DD], shs[DD];
    __shared__ float pa[NPG], pb[NPG];
    __shared__ float pw[EPG];
    __shared__ int ord[EPG];
    const int b = blockIdx.x, t = threadIdx.x;
    {
        const int c = t & 255, half = t >> 8;
        double s = 0.0, q = 0.0;
#pragma unroll 4
        for (int k = half * 128; k < half * 128 + 128; ++k) {
            s += (double)psum[(size_t)k * DD + c];
            q += (double)psumsq[(size_t)k * DD + c];
        }
        redS[half][c] = s;
        redQ[half][c] = q;
    }
    __syncthreads();
    if (t < DD) {
        const double s = redS[0][t] + redS[1][t];
        const double q = redQ[0][t] + redQ[1][t];
        const double mean = s / (double)NTOT;
        const double var = q / (double)NTOT - mean * mean;
        const double rs = 1.0 / sqrt(var + 1e-5);
        const float sc = (float)((double)g[t] * rs);
        scs[t] = sc;
        shs[t] = (float)((double)be[t] - mean * (double)sc);
    }
    __syncthreads();
    {
        const int wave = t >> 6, lane = t & 63;
        const float4 w0 = *(const float4*)&Wl[lane * 4];
        const float4 w1 = *(const float4*)&Wl[DD + lane * 4];
        const float4 sc4 = *(const float4*)&scs[lane * 4];
        const float4 sh4 = *(const float4*)&shs[lane * 4];
        for (int n = wave; n < NPG; n += 8) {
            const us4 z4 = *(const us4*)&h2[(size_t)(b * NPG + n) * DD + lane * 4];
            const float x0 = fmaf(bf2f(z4.x), sc4.x, sh4.x);
            const float x1 = fmaf(bf2f(z4.y), sc4.y, sh4.y);
            const float x2 = fmaf(bf2f(z4.z), sc4.z, sh4.z);
            const float x3 = fmaf(bf2f(z4.w), sc4.w, sh4.w);
            float sa = x0 * w0.x + x1 * w0.y + x2 * w0.z + x3 * w0.w;
            float sb = x0 * w1.x + x1 * w1.y + x2 * w1.z + x3 * w1.w;
#pragma unroll
            for (int off = 32; off >= 1; off >>= 1) {
                sa += __shfl_down(sa, off);
                sb += __shfl_down(sb, off);
            }
            if (lane == 0) { pa[n] = sa; pb[n] = sb; }
        }
    }
    __syncthreads();
    const int rl = ei[b * EPG + t] - b * NPG;
    const int cl = ei[ETOT + b * EPG + t] - b * NPG;
    const float v = pa[rl] + pb[cl] + bl[0];
    pw[t] = v;
    out[OFF_PRED + b * EPG + t] = v;
    __syncthreads();
    int rank = 0;
#pragma unroll 8
    for (int k = 0; k < EPG; ++k) {
        const float u = pw[k];
        rank += (u > v) || (u == v && k < t);
    }
    ord[rank] = t;
    __syncthreads();
    const int j = ord[t];
    const float wv = pw[j];
    const float e0 = (float)ei[b * EPG + j];
    const float e1 = (float)ei[ETOT + b * EPG + j];
    if (t < NRES) {
        out[OFF_CEI + b * NRES + t] = e0;
        out[OFF_CEI + BGR * NRES + b * NRES + t] = e1;
        out[OFF_CW + b * NRES + t] = wv;
    } else {
        const int p = t - NRES;
        out[OFF_FEI + b * NRES + p] = e0;
        out[OFF_FEI + BGR * NRES + b * NRES + p] = e1;
        out[OFF_FW + b * NRES + p] = -wv;
    }
}

// ---------------------------------------------------------------------------
extern "C" void kernel_launch(void* const* d_in, const int* in_sizes, int n_in,
                              void* d_out, int out_size, void* d_ws, size_t ws_size,
                              hipStream_t stream) {
    (void)in_sizes; (void)n_in; (void)out_size; (void)ws_size;
    const float* x    = (const float*)d_in[0];
    const int*   ei   = (const int*)d_in[1];
    const float* vemb = (const float*)d_in[3];
    const float* W1a  = (const float*)d_in[4];
    const float* b1a  = (const float*)d_in[5];
    const float* g1a  = (const float*)d_in[6];
    const float* be1a = (const float*)d_in[7];
    const float* W1b  = (const float*)d_in[8];
    const float* b1b  = (const float*)d_in[9];
    const float* g1   = (const float*)d_in[10];
    const float* be1  = (const float*)d_in[11];
    const float* W2a  = (const float*)d_in[12];
    const float* b2a  = (const float*)d_in[13];
    const float* g2a  = (const float*)d_in[14];
    const float* be2a = (const float*)d_in[15];
    const float* W2b  = (const float*)d_in[16];
    const float* b2b  = (const float*)d_in[17];
    const float* g2   = (const float*)d_in[18];
    const float* be2  = (const float*)d_in[19];
    const float* Wl   = (const float*)d_in[20];
    const float* bl   = (const float*)d_in[21];
    float* out = (float*)d_out;

    char* wp = (char*)d_ws;
    auto alloc = [&](size_t bytes) -> char* {
        char* r = wp;
        wp += (bytes + 255) & ~(size_t)255;
        return r;
    };
    ushortt* zb    = (ushortt*)alloc((size_t)NTOT * 512 * 2);  // z1 / z2
    ushortt* bufC  = (ushortt*)alloc((size_t)NTOT * 256 * 2);  // h1 / h2
    ushortt* bufS1 = (ushortt*)alloc((size_t)NTOT * 128 * 2);  // s1
    ushortt* bufS2 = (ushortt*)alloc((size_t)NTOT * 256 * 2);  // s2
    ushortt* Wt1a  = (ushortt*)alloc((size_t)DIN * DD2 * 2);
    ushortt* Wt1b  = (ushortt*)alloc((size_t)DD2 * DD * 2);
    ushortt* Wt2a  = (ushortt*)alloc((size_t)DD * DD2 * 2);
    ushortt* Wt2b  = (ushortt*)alloc((size_t)DD2 * DD * 2);
    float*   psA   = (float*)alloc((size_t)256 * DD2 * 4);
    float*   pqA   = (float*)alloc((size_t)256 * DD2 * 4);
    float*   psB   = (float*)alloc((size_t)256 * DD * 4);
    float*   pqB   = (float*)alloc((size_t)256 * DD * 4);
    float*   scA   = (float*)alloc(DD2 * 4);
    float*   shA   = (float*)alloc(DD2 * 4);

    // 1) weights (tiled transpose) + (adjacency, s1) in one dispatch
    prep<<<368, 256, 0, stream>>>(W1a, W1b, W2a, W2b, x, ei,
                                  Wt1a, Wt1b, Wt2a, Wt2b, bufS1);

    // 2) z1 = s1 @ W1a + b1a (+stats)
    gemm_mfma<<<dim3(DD2 / BN, NTOT / BM), 256, 0, stream>>>(bufS1, Wt1a, b1a, zb, psA, pqA, NTOT, DD2, DIN);
    bn_finalize<<<2, 256, 0, stream>>>(psA, pqA, g1a, be1a, DD2, scA, shA);

    // 3) h1 = relu(BN(z1)) @ W1b + b1b (+stats)
    gemm_bn<<<dim3(DD / BN, NTOT / BM), 256, 0, stream>>>(zb, Wt1b, scA, shA, b1b, bufC, psB, pqB);

    // 4) s2 = M @ (relu(BN(h1)) + vemb)  [adjacency rebuilt in-block]
    agg2_mm<<<dim3(2, BGR), 256, 0, stream>>>(bufC, psB, pqB, g1, be1, vemb, ei, bufS2);

    // 5) z2 = s2 @ W2a + b2a (+stats)
    gemm_mfma<<<dim3(DD2 / BN, NTOT / BM), 256, 0, stream>>>(bufS2, Wt2a, b2a, zb, psA, pqA, NTOT, DD2, DD);
    bn_finalize<<<2, 256, 0, stream>>>(psA, pqA, g2a, be2a, DD2, scA, shA);

    // 6) h2 = relu(BN(z2)) @ W2b + b2b (+stats)
    gemm_bn<<<dim3(DD / BN, NTOT / BM), 256, 0, stream>>>(zb, Wt2b, scA, shA, b2b, bufC, psB, pqB);

    // 7) mega tail (finalize(g2) fused)
    sort_mega<<<BGR, EPG, 0, stream>>>(bufC, psB, pqB, g2, be2, Wl, bl, ei, out);
}